// Round 4
// baseline (22156.416 us; speedup 1.0000x reference)
//
#include <hip/hip_runtime.h>

#define B_    16
#define CIN_  512
#define CF_   64
#define FH_   11
#define FW_   20
#define N_    2784
#define NM1_  2783
#define D_    704
#define D2_   1408
#define ROWS_ 44544
#define PW_   77

// ---- input element counts
#define NX_     1802240
#define NCW_    32768
#define NCB_    64
#define NATTW_  1959232
#define NATTB_  2783
#define NCLSW_  2816
#define NCLSB_  2
#define NREGW_  102784
#define NREGB_  73
#define NANCH_  214368
#define NCUT_   30624

// ---- canonical ws layout (byte offsets)
#define OFF_FLAGS   0u
#define OFF_FEAT    256u
#define OFF_CANON   (1u<<20)
#define C_X      0u
#define C_ATTW   3604480u
#define C_CW     7522944u
#define C_ANCH   7588480u
#define C_CLSW   8017216u
#define C_REGW   8022848u
#define C_CB     8228416u
#define C_ATTB   8228544u
#define C_CLSB   8234112u
#define C_REGB   8234128u
#define C_CUT    8234288u
#define C_MASK   8356784u

__device__ __forceinline__ float bf2f(unsigned short u) {
    union { unsigned int u; float f; } v; v.u = ((unsigned int)u) << 16; return v.f;
}
__device__ __forceinline__ unsigned short f2bf(float f) {
    union { float f; unsigned int u; } v; v.f = f;
    unsigned int x = v.u;
    return (unsigned short)((x + 0x7FFFu + ((x >> 16) & 1u)) >> 16);
}

// ---------------- K0: dtype detection (deterministic, input-only)
__global__ __launch_bounds__(256) void k_detect(const unsigned int* __restrict__ attw,
                                                const unsigned int* __restrict__ cut,
                                                const unsigned int* __restrict__ msk,
                                                int* __restrict__ flags) {
    __shared__ int cnt[3];
    int t = threadIdx.x;
    if (t < 3) cnt[t] = 0;
    __syncthreads();
    int c0 = 0, c1 = 0, c2 = 0;
    for (int i = t; i < 2048; i += 256) {
        unsigned int e = (attw[i] >> 7) & 0xFFu;   // bf16-low exponent field
        if (e >= 127u) c0++;                        // impossible for genuine attn_w bf16
    }
    for (int i = t; i < 4096; i += 256) if (cut[i] >= 32u) c1++;
    for (int i = t; i < 4096; i += 256) if (msk[i] >= 2u)  c2++;
    atomicAdd(&cnt[0], c0); atomicAdd(&cnt[1], c1); atomicAdd(&cnt[2], c2);
    __syncthreads();
    if (t == 0) {
        flags[0] = cnt[0] > 64;   // float inputs are f32 (not bf16)
        flags[1] = cnt[1] > 64;   // cut is byte-packed
        flags[2] = cnt[2] > 64;   // mask is byte-packed
        flags[3] = 0;
    }
}

// ---------------- K0b: canonicalize all float inputs to bf16
__device__ __forceinline__ void cvt_arr(const void* s, unsigned short* d, int n, int isf32,
                                        int tid, int stride) {
    if (isf32) {
        const float* p = (const float*)s;
        for (int i = tid; i < n; i += stride) d[i] = f2bf(p[i]);
    } else {
        const unsigned short* p = (const unsigned short*)s;
        for (int i = tid; i < n; i += stride) d[i] = p[i];
    }
}

__global__ __launch_bounds__(256) void k_canon_f(const void* sx, const void* scw, const void* scb,
                                                 const void* sattw, const void* sattb,
                                                 const void* sclsw, const void* sclsb,
                                                 const void* sregw, const void* sregb,
                                                 const void* sanch, char* canon,
                                                 const int* __restrict__ flags) {
    const int isf32 = flags[0];
    const int tid = blockIdx.x * 256 + threadIdx.x;
    const int stride = gridDim.x * 256;
    cvt_arr(sx,    (unsigned short*)(canon + C_X),    NX_,    isf32, tid, stride);
    cvt_arr(sattw, (unsigned short*)(canon + C_ATTW), NATTW_, isf32, tid, stride);
    cvt_arr(scw,   (unsigned short*)(canon + C_CW),   NCW_,   isf32, tid, stride);
    cvt_arr(sanch, (unsigned short*)(canon + C_ANCH), NANCH_, isf32, tid, stride);
    cvt_arr(sclsw, (unsigned short*)(canon + C_CLSW), NCLSW_, isf32, tid, stride);
    cvt_arr(sregw, (unsigned short*)(canon + C_REGW), NREGW_, isf32, tid, stride);
    cvt_arr(scb,   (unsigned short*)(canon + C_CB),   NCB_,   isf32, tid, stride);
    cvt_arr(sattb, (unsigned short*)(canon + C_ATTB), NATTB_, isf32, tid, stride);
    cvt_arr(sclsb, (unsigned short*)(canon + C_CLSB), NCLSB_, isf32, tid, stride);
    cvt_arr(sregb, (unsigned short*)(canon + C_REGB), NREGB_, isf32, tid, stride);
}

// ---------------- K0c: canonicalize int inputs to int32
__global__ __launch_bounds__(256) void k_canon_i(const void* scut, const void* smsk,
                                                 char* canon, const int* __restrict__ flags) {
    const int cutb = flags[1], mskb = flags[2];
    int* ccut = (int*)(canon + C_CUT);
    int* cmsk = (int*)(canon + C_MASK);
    const int tid = blockIdx.x * 256 + threadIdx.x;
    const int stride = gridDim.x * 256;
    for (int i = tid; i < NCUT_; i += stride) {
        ccut[i] = cutb ? (int)((const unsigned char*)scut)[i] : ((const int*)scut)[i];
        int m = mskb ? (int)((const unsigned char*)smsk)[i] : ((const int*)smsk)[i];
        cmsk[i] = (m != 0);
    }
}

// ---------------- K1: 1x1 conv
__global__ __launch_bounds__(256) void k_conv(const unsigned short* __restrict__ x,
                                              const unsigned short* __restrict__ cw,
                                              const unsigned short* __restrict__ cb,
                                              float* __restrict__ feat) {
    int idx = blockIdx.x * 256 + threadIdx.x;           // 880*256 = 225280 exact
    int w = idx % FW_;
    int h = (idx / FW_) % FH_;
    int o = (idx / (FW_ * FH_)) % CF_;
    int b = idx / (FW_ * FH_ * CF_);
    const unsigned short* xp = x + ((size_t)(b * CIN_) * FH_ + h) * FW_ + w;
    const unsigned short* wp = cw + (size_t)o * CIN_;
    float acc = bf2f(cb[o]);
#pragma unroll 8
    for (int c = 0; c < CIN_; ++c)
        acc += bf2f(xp[(size_t)c * (FH_ * FW_)]) * bf2f(wp[c]);
    feat[idx] = acc;
}

// ---------------- K2a: AF chunk
__global__ __launch_bounds__(256) void k_gather_af(const float* __restrict__ feat,
                                                   const int* __restrict__ cut,
                                                   const int* __restrict__ inv,
                                                   unsigned short* __restrict__ AF,
                                                   int batch_base) {
    int n = blockIdx.x, bl = blockIdx.y;
    int b = batch_base + bl;
    __shared__ int cu[FH_];
    __shared__ int iv[FH_];
    int t = threadIdx.x;
    if (t < FH_) { cu[t] = cut[n * FH_ + t]; iv[t] = inv[n * FH_ + t]; }
    __syncthreads();
    unsigned short* out = AF + ((size_t)(bl * N_ + n)) * D_;
    for (int d = t; d < D_; d += 256) {
        int c = d / FH_, h = d - c * FH_;
        float v = iv[h] ? 0.f : feat[((b * CF_ + c) * FH_ + h) * FW_ + cu[h]];
        out[d] = f2bf(v);
    }
}

// ---------------- K2b: AFT chunk
__global__ __launch_bounds__(256) void k_gather_aft(const float* __restrict__ feat,
                                                    const int* __restrict__ cut,
                                                    const int* __restrict__ inv,
                                                    unsigned short* __restrict__ AFT,
                                                    int batch_base) {
    int d = blockIdx.x, bl = blockIdx.y;
    int b = batch_base + bl;
    int c = d / FH_, h = d - c * FH_;
    const float* fp = feat + ((b * CF_ + c) * FH_ + h) * FW_;
    unsigned short* out = AFT + ((size_t)(bl * D_ + d)) * N_;
    for (int n = threadIdx.x; n < N_; n += 256) {
        int w = cut[n * FH_ + h];
        float v = inv[n * FH_ + h] ? 0.f : fp[w];
        out[n] = f2bf(v);
    }
}

// ---------------- K3a: scores GEMM + shifted scatter into M (f32)
__global__ __launch_bounds__(256) void k_scores_s(const unsigned short* __restrict__ AF,
                                                  const unsigned short* __restrict__ attw,
                                                  const unsigned short* __restrict__ attb,
                                                  float* __restrict__ Mbuf,
                                                  int row_base, int nloc) {
    __shared__ float As[16][65];
    __shared__ float Bs[64][65];
    const int t = threadIdx.x;
    const int ty = t >> 4, tx = t & 15;
    const int i0 = blockIdx.y * 16, j0 = blockIdx.x * 64;
    float acc[4] = {0.f, 0.f, 0.f, 0.f};

    for (int k0 = 0; k0 < D_; k0 += 64) {
        for (int e = t; e < 16 * 64; e += 256) {
            int r = e >> 6, k = e & 63;
            int ir = i0 + r; if (ir > nloc - 1) ir = nloc - 1;
            As[r][k] = bf2f(AF[(size_t)ir * D_ + k0 + k]);
        }
        for (int e = t; e < 64 * 64; e += 256) {
            int r = e >> 6, k = e & 63;
            int jr = j0 + r; if (jr > NM1_ - 1) jr = NM1_ - 1;
            Bs[r][k] = bf2f(attw[(size_t)jr * D_ + k0 + k]);
        }
        __syncthreads();
#pragma unroll
        for (int kk = 0; kk < 64; ++kk) {
            float av = As[ty][kk];
            acc[0] += av * Bs[tx][kk];
            acc[1] += av * Bs[tx + 16][kk];
            acc[2] += av * Bs[tx + 32][kk];
            acc[3] += av * Bs[tx + 48][kk];
        }
        __syncthreads();
    }

    int i = i0 + ty;
    if (i < nloc) {
        int r = i % N_;
        size_t rowoff = (size_t)(row_base + i) * N_;
#pragma unroll
        for (int jj = 0; jj < 4; ++jj) {
            int j = j0 + tx + 16 * jj;
            if (j < NM1_) {
                float v = acc[jj] + bf2f(attb[j]);
                int c = j + (j >= r);
                Mbuf[rowoff + c] = v;
            }
        }
    }
}

// ---------------- K3b: in-place f32 row softmax over M rows (diag -> exact 0)
__global__ __launch_bounds__(256) void k_softmax(float* __restrict__ Mbuf, int row_base) {
    const int i = row_base + blockIdx.x;
    const int r = i % N_;
    float* row = Mbuf + (size_t)i * N_;
    const int t = threadIdx.x;
    float f[11];
#pragma unroll
    for (int q = 0; q < 11; ++q) {
        int c = t + 256 * q;
        float a = (c < N_) ? row[c] : -1e30f;
        if (c == r) a = -1e30f;
        f[q] = a;
    }
    float m = -1e30f;
#pragma unroll
    for (int q = 0; q < 11; ++q) m = fmaxf(m, f[q]);
#pragma unroll
    for (int off = 32; off >= 1; off >>= 1) m = fmaxf(m, __shfl_xor(m, off, 64));
    __shared__ float red[4];
    if ((t & 63) == 0) red[t >> 6] = m;
    __syncthreads();
    m = fmaxf(fmaxf(red[0], red[1]), fmaxf(red[2], red[3]));

    float s = 0.f;
#pragma unroll
    for (int q = 0; q < 11; ++q) { float e = __expf(f[q] - m); f[q] = e; s += e; }
#pragma unroll
    for (int off = 32; off >= 1; off >>= 1) s += __shfl_xor(s, off, 64);
    __shared__ float red2[4];
    if ((t & 63) == 0) red2[t >> 6] = s;
    __syncthreads();
    s = red2[0] + red2[1] + red2[2] + red2[3];
    float inv = 1.0f / s;
#pragma unroll
    for (int q = 0; q < 11; ++q) {
        int c = t + 256 * q;
        if (c < N_) row[c] = f[q] * inv;   // diag: exp(-1e30-m)=0 -> exact 0
    }
}

// ---------------- K4: att_feat = M(f32) @ AF  (B^T operand = AFT)
__global__ __launch_bounds__(256) void k_attgemm_s(const float* __restrict__ Mbuf,
                                                   const unsigned short* __restrict__ AFT,
                                                   unsigned short* __restrict__ ATF,
                                                   int batch_base) {
    __shared__ float As[16][65];
    __shared__ float Bs[64][65];
    const int t = threadIdx.x;
    const int ty = t >> 4, tx = t & 15;
    const int i0 = blockIdx.y * 16, j0 = blockIdx.x * 64;
    const int bl = blockIdx.z, bg = batch_base + bl;
    float acc[4] = {0.f, 0.f, 0.f, 0.f};

    for (int k0 = 0; k0 < N_; k0 += 64) {
        for (int e = t; e < 16 * 64; e += 256) {
            int r = e >> 6, k = e & 63;
            int ir = i0 + r; if (ir > N_ - 1) ir = N_ - 1;
            int ka = k0 + k;
            As[r][k] = (ka < N_) ? Mbuf[(size_t)(bg * N_ + ir) * N_ + ka] : 0.f;
        }
        for (int e = t; e < 64 * 64; e += 256) {
            int r = e >> 6, k = e & 63;
            int jr = j0 + r; if (jr > D_ - 1) jr = D_ - 1;
            int ka = k0 + k;
            Bs[r][k] = (ka < N_) ? bf2f(AFT[(size_t)(bl * D_ + jr) * N_ + ka]) : 0.f;
        }
        __syncthreads();
#pragma unroll
        for (int kk = 0; kk < 64; ++kk) {
            float av = As[ty][kk];
            acc[0] += av * Bs[tx][kk];
            acc[1] += av * Bs[tx + 16][kk];
            acc[2] += av * Bs[tx + 32][kk];
            acc[3] += av * Bs[tx + 48][kk];
        }
        __syncthreads();
    }

    int i = i0 + ty;
    if (i < N_) {
#pragma unroll
        for (int jj = 0; jj < 4; ++jj) {
            int j = j0 + tx + 16 * jj;
            if (j < D_)
                ATF[((size_t)(bl * N_ + i)) * D_ + j] = f2bf(acc[jj]);
        }
    }
}

// ---------------- K5: heads + fused props epilogue (f32 out)
__global__ __launch_bounds__(256) void k_head_s(const unsigned short* __restrict__ ATF,
                                                const unsigned short* __restrict__ AF,
                                                const unsigned short* __restrict__ clsw,
                                                const unsigned short* __restrict__ clsb,
                                                const unsigned short* __restrict__ regw,
                                                const unsigned short* __restrict__ regb,
                                                const unsigned short* __restrict__ anch,
                                                float* __restrict__ props,
                                                int row_base, int nloc) {
    __shared__ float As[16][65];
    __shared__ float Bs[80][65];
    const int t = threadIdx.x;
    const int ty = t >> 4, tx = t & 15;
    const int i0 = blockIdx.x * 16;
    float acc[5] = {0.f, 0.f, 0.f, 0.f, 0.f};

    for (int k0 = 0; k0 < D2_; k0 += 64) {
        for (int e = t; e < 16 * 64; e += 256) {
            int r = e >> 6, k = e & 63;
            int ir = i0 + r; if (ir > nloc - 1) ir = nloc - 1;
            int ka = k0 + k;
            As[r][k] = (ka < D_) ? bf2f(ATF[(size_t)ir * D_ + ka])
                                 : bf2f(AF[(size_t)ir * D_ + ka - D_]);
        }
        for (int e = t; e < 80 * 64; e += 256) {
            int r = e >> 6, k = e & 63;
            int jr = r; if (jr > 74) jr = 74;
            int ka = k0 + k;
            Bs[r][k] = (jr < 2) ? bf2f(clsw[(size_t)jr * D2_ + ka])
                                : bf2f(regw[(size_t)(jr - 2) * D2_ + ka]);
        }
        __syncthreads();
#pragma unroll
        for (int kk = 0; kk < 64; ++kk) {
            float av = As[ty][kk];
            acc[0] += av * Bs[tx][kk];
            acc[1] += av * Bs[tx + 16][kk];
            acc[2] += av * Bs[tx + 32][kk];
            acc[3] += av * Bs[tx + 48][kk];
            acc[4] += av * Bs[tx + 64][kk];
        }
        __syncthreads();
    }

    int i = i0 + ty;
    if (i < nloc) {
        size_t g = (size_t)(row_base + i);
        int nn = i % N_;
#pragma unroll
        for (int jj = 0; jj < 5; ++jj) {
            int j = tx + 16 * jj;
            if (j < 75) {
                float v = acc[jj];
                if (j < 2) {
                    props[g * PW_ + j] = v + bf2f(clsb[j]);
                    props[g * PW_ + 2 + j] = bf2f(anch[(size_t)nn * PW_ + 2 + j]);
                } else {
                    int tt = j - 2;
                    props[g * PW_ + 4 + tt] = v + bf2f(regb[tt]) + bf2f(anch[(size_t)nn * PW_ + 4 + tt]);
                }
            }
        }
    }
}

extern "C" void kernel_launch(void* const* d_in, const int* in_sizes, int n_in,
                              void* d_out, int out_size, void* d_ws, size_t ws_size,
                              hipStream_t stream) {
    (void)in_sizes; (void)n_in; (void)out_size;

    float* props = (float*)d_out;                       // f32 output!
    float* Mbuf  = props + (size_t)ROWS_ * PW_;

    char* ws = (char*)d_ws;
    int* flags = (int*)(ws + OFF_FLAGS);
    float* feat = (float*)(ws + OFF_FEAT);
    char* canon = ws + OFF_CANON;
    unsigned short* cx    = (unsigned short*)(canon + C_X);
    unsigned short* cattw = (unsigned short*)(canon + C_ATTW);
    unsigned short* ccw   = (unsigned short*)(canon + C_CW);
    unsigned short* canch = (unsigned short*)(canon + C_ANCH);
    unsigned short* cclsw = (unsigned short*)(canon + C_CLSW);
    unsigned short* cregw = (unsigned short*)(canon + C_REGW);
    unsigned short* ccb   = (unsigned short*)(canon + C_CB);
    unsigned short* cattb = (unsigned short*)(canon + C_ATTB);
    unsigned short* cclsb = (unsigned short*)(canon + C_CLSB);
    unsigned short* cregb = (unsigned short*)(canon + C_REGB);
    int* ccut = (int*)(canon + C_CUT);
    int* cmsk = (int*)(canon + C_MASK);

    size_t base = (size_t)(12u << 20);
    size_t sa16 = (size_t)16 * N_ * D_ * 2;
    size_t sa4  = (size_t)4  * N_ * D_ * 2;
    int CN = (ws_size >= base + 3 * sa16) ? 16 : (ws_size >= base + 3 * sa4) ? 4 : 1;
    size_t SA = (size_t)CN * N_ * D_ * 2;
    unsigned short* AF  = (unsigned short*)(ws + base);
    unsigned short* AFT = (unsigned short*)(ws + base + SA);
    unsigned short* ATF = (unsigned short*)(ws + base + 2 * SA);

    k_detect<<<dim3(1), dim3(256), 0, stream>>>((const unsigned int*)d_in[3],
                                                (const unsigned int*)d_in[10],
                                                (const unsigned int*)d_in[11], flags);
    k_canon_f<<<dim3(1024), dim3(256), 0, stream>>>(d_in[0], d_in[1], d_in[2], d_in[3], d_in[4],
                                                    d_in[5], d_in[6], d_in[7], d_in[8], d_in[9],
                                                    canon, flags);
    k_canon_i<<<dim3(120), dim3(256), 0, stream>>>(d_in[10], d_in[11], canon, flags);
    k_conv<<<dim3(880), dim3(256), 0, stream>>>(cx, ccw, ccb, feat);

    const int nchunk = 16 / CN;
    for (int c = 0; c < nchunk; ++c) {
        const int bb = c * CN;
        const int rb = bb * N_;
        const int nl = CN * N_;
        const int it16 = (nl + 15) / 16;
        k_gather_af<<<dim3(N_, CN), dim3(256), 0, stream>>>(feat, ccut, cmsk, AF, bb);
        k_gather_aft<<<dim3(D_, CN), dim3(256), 0, stream>>>(feat, ccut, cmsk, AFT, bb);
        k_scores_s<<<dim3(44, it16), dim3(256), 0, stream>>>(AF, cattw, cattb, Mbuf, rb, nl);
        k_softmax<<<dim3(nl), dim3(256), 0, stream>>>(Mbuf, rb);
        k_attgemm_s<<<dim3(11, 174, CN), dim3(256), 0, stream>>>(Mbuf, AFT, ATF, bb);
        k_head_s<<<dim3(it16), dim3(256), 0, stream>>>(ATF, AF, cclsw, cclsb, cregw, cregb,
                                                       canch, props, rb, nl);
    }
}

// Round 5
// 1269.379 us; speedup vs baseline: 17.4545x; 17.4545x over previous
//
#include <hip/hip_runtime.h>

#define B_    16
#define CIN_  512
#define CF_   64
#define FH_   11
#define FW_   20
#define N_    2784
#define NM1_  2783
#define D_    704
#define D2_   1408
#define ROWS_ 44544
#define PW_   77

// ---- input element counts
#define NX_     1802240
#define NCW_    32768
#define NCB_    64
#define NATTW_  1959232
#define NATTB_  2783
#define NCLSW_  2816
#define NCLSB_  2
#define NREGW_  102784
#define NREGB_  73
#define NANCH_  214368
#define NCUT_   30624

// ---- canonical ws layout (byte offsets)
#define OFF_FLAGS   0u
#define OFF_FEAT    256u
#define OFF_CANON   (1u<<20)
#define C_X      0u
#define C_ATTW   3604480u
#define C_CW     7522944u
#define C_ANCH   7588480u
#define C_CLSW   8017216u
#define C_REGW   8022848u
#define C_CB     8228416u
#define C_ATTB   8228544u
#define C_CLSB   8234112u
#define C_REGB   8234128u
#define C_CUT    8234288u
#define C_MASK   8356784u

typedef __bf16 bf16x8 __attribute__((ext_vector_type(8)));
typedef float  f32x4  __attribute__((ext_vector_type(4)));

typedef __attribute__((address_space(1))) void g_void;
typedef __attribute__((address_space(3))) void l_void;
#define GLD16(gp, lp) __builtin_amdgcn_global_load_lds((g_void*)(gp), (l_void*)(lp), 16, 0, 0)

__device__ __forceinline__ float bf2f(unsigned short u) {
    union { unsigned int u; float f; } v; v.u = ((unsigned int)u) << 16; return v.f;
}
__device__ __forceinline__ unsigned short f2bf(float f) {
    union { float f; unsigned int u; } v; v.f = f;
    unsigned int x = v.u;
    return (unsigned short)((x + 0x7FFFu + ((x >> 16) & 1u)) >> 16);
}

// ---------------- K0: dtype detection (deterministic, input-only)
__global__ __launch_bounds__(256) void k_detect(const unsigned int* __restrict__ attw,
                                                const unsigned int* __restrict__ cut,
                                                const unsigned int* __restrict__ msk,
                                                int* __restrict__ flags) {
    __shared__ int cnt[3];
    int t = threadIdx.x;
    if (t < 3) cnt[t] = 0;
    __syncthreads();
    int c0 = 0, c1 = 0, c2 = 0;
    for (int i = t; i < 2048; i += 256) {
        unsigned int e = (attw[i] >> 7) & 0xFFu;
        if (e >= 127u) c0++;
    }
    for (int i = t; i < 4096; i += 256) if (cut[i] >= 32u) c1++;
    for (int i = t; i < 4096; i += 256) if (msk[i] >= 2u)  c2++;
    atomicAdd(&cnt[0], c0); atomicAdd(&cnt[1], c1); atomicAdd(&cnt[2], c2);
    __syncthreads();
    if (t == 0) {
        flags[0] = cnt[0] > 64;
        flags[1] = cnt[1] > 64;
        flags[2] = cnt[2] > 64;
        flags[3] = 0;
    }
}

// ---------------- K0b: canonicalize all float inputs to bf16
__device__ __forceinline__ void cvt_arr(const void* s, unsigned short* d, int n, int isf32,
                                        int tid, int stride) {
    if (isf32) {
        const float* p = (const float*)s;
        for (int i = tid; i < n; i += stride) d[i] = f2bf(p[i]);
    } else {
        const unsigned short* p = (const unsigned short*)s;
        for (int i = tid; i < n; i += stride) d[i] = p[i];
    }
}

__global__ __launch_bounds__(256) void k_canon_f(const void* sx, const void* scw, const void* scb,
                                                 const void* sattw, const void* sattb,
                                                 const void* sclsw, const void* sclsb,
                                                 const void* sregw, const void* sregb,
                                                 const void* sanch, char* canon,
                                                 const int* __restrict__ flags) {
    const int isf32 = flags[0];
    const int tid = blockIdx.x * 256 + threadIdx.x;
    const int stride = gridDim.x * 256;
    cvt_arr(sx,    (unsigned short*)(canon + C_X),    NX_,    isf32, tid, stride);
    cvt_arr(sattw, (unsigned short*)(canon + C_ATTW), NATTW_, isf32, tid, stride);
    cvt_arr(scw,   (unsigned short*)(canon + C_CW),   NCW_,   isf32, tid, stride);
    cvt_arr(sanch, (unsigned short*)(canon + C_ANCH), NANCH_, isf32, tid, stride);
    cvt_arr(sclsw, (unsigned short*)(canon + C_CLSW), NCLSW_, isf32, tid, stride);
    cvt_arr(sregw, (unsigned short*)(canon + C_REGW), NREGW_, isf32, tid, stride);
    cvt_arr(scb,   (unsigned short*)(canon + C_CB),   NCB_,   isf32, tid, stride);
    cvt_arr(sattb, (unsigned short*)(canon + C_ATTB), NATTB_, isf32, tid, stride);
    cvt_arr(sclsb, (unsigned short*)(canon + C_CLSB), NCLSB_, isf32, tid, stride);
    cvt_arr(sregb, (unsigned short*)(canon + C_REGB), NREGB_, isf32, tid, stride);
}

// ---------------- K0c: canonicalize int inputs to int32
__global__ __launch_bounds__(256) void k_canon_i(const void* scut, const void* smsk,
                                                 char* canon, const int* __restrict__ flags) {
    const int cutb = flags[1], mskb = flags[2];
    int* ccut = (int*)(canon + C_CUT);
    int* cmsk = (int*)(canon + C_MASK);
    const int tid = blockIdx.x * 256 + threadIdx.x;
    const int stride = gridDim.x * 256;
    for (int i = tid; i < NCUT_; i += stride) {
        ccut[i] = cutb ? (int)((const unsigned char*)scut)[i] : ((const int*)scut)[i];
        int m = mskb ? (int)((const unsigned char*)smsk)[i] : ((const int*)smsk)[i];
        cmsk[i] = (m != 0);
    }
}

// ---------------- K1: 1x1 conv
__global__ __launch_bounds__(256) void k_conv(const unsigned short* __restrict__ x,
                                              const unsigned short* __restrict__ cw,
                                              const unsigned short* __restrict__ cb,
                                              float* __restrict__ feat) {
    int idx = blockIdx.x * 256 + threadIdx.x;           // 880*256 = 225280 exact
    int w = idx % FW_;
    int h = (idx / FW_) % FH_;
    int o = (idx / (FW_ * FH_)) % CF_;
    int b = idx / (FW_ * FH_ * CF_);
    const unsigned short* xp = x + ((size_t)(b * CIN_) * FH_ + h) * FW_ + w;
    const unsigned short* wp = cw + (size_t)o * CIN_;
    float acc = bf2f(cb[o]);
#pragma unroll 8
    for (int c = 0; c < CIN_; ++c)
        acc += bf2f(xp[(size_t)c * (FH_ * FW_)]) * bf2f(wp[c]);
    feat[idx] = acc;
}

// ---------------- K2a: AF chunk
__global__ __launch_bounds__(256) void k_gather_af(const float* __restrict__ feat,
                                                   const int* __restrict__ cut,
                                                   const int* __restrict__ inv,
                                                   unsigned short* __restrict__ AF,
                                                   int batch_base) {
    int n = blockIdx.x, bl = blockIdx.y;
    int b = batch_base + bl;
    __shared__ int cu[FH_];
    __shared__ int iv[FH_];
    int t = threadIdx.x;
    if (t < FH_) { cu[t] = cut[n * FH_ + t]; iv[t] = inv[n * FH_ + t]; }
    __syncthreads();
    unsigned short* out = AF + ((size_t)(bl * N_ + n)) * D_;
    for (int d = t; d < D_; d += 256) {
        int c = d / FH_, h = d - c * FH_;
        float v = iv[h] ? 0.f : feat[((b * CF_ + c) * FH_ + h) * FW_ + cu[h]];
        out[d] = f2bf(v);
    }
}

// ---------------- K2b: AFT chunk
__global__ __launch_bounds__(256) void k_gather_aft(const float* __restrict__ feat,
                                                    const int* __restrict__ cut,
                                                    const int* __restrict__ inv,
                                                    unsigned short* __restrict__ AFT,
                                                    int batch_base) {
    int d = blockIdx.x, bl = blockIdx.y;
    int b = batch_base + bl;
    int c = d / FH_, h = d - c * FH_;
    const float* fp = feat + ((b * CF_ + c) * FH_ + h) * FW_;
    unsigned short* out = AFT + ((size_t)(bl * D_ + d)) * N_;
    for (int n = threadIdx.x; n < N_; n += 256) {
        int w = cut[n * FH_ + h];
        float v = inv[n * FH_ + h] ? 0.f : fp[w];
        out[n] = f2bf(v);
    }
}

// ---------------- K3a: MFMA scores GEMM, shifted-scatter into M (f32)
__global__ __launch_bounds__(256) void k_scores(const unsigned short* __restrict__ AF,
                                                const unsigned short* __restrict__ attw,
                                                const unsigned short* __restrict__ attb,
                                                float* __restrict__ Mbuf,
                                                int row_base, int nloc) {
    __shared__ __bf16 As[128 * 32];
    __shared__ __bf16 Bs[128 * 32];
    const int t = threadIdx.x;
    const int jt = blockIdx.x, it = blockIdx.y;
    const int i0 = it * 128, j0 = jt * 128;
    const int lane = t & 63, wv = t >> 6;
    const int wr = wv >> 1, wc = wv & 1;
    const int l15 = lane & 15, hi8 = (lane >> 4) * 8;

    f32x4 zero = {0.f, 0.f, 0.f, 0.f};
    f32x4 acc[4][4];
#pragma unroll
    for (int m = 0; m < 4; ++m)
#pragma unroll
        for (int n = 0; n < 4; ++n) acc[m][n] = zero;

    const int s0 = t, s1 = t + 256;
    const int ar0 = s0 >> 2, ac0 = (s0 & 3) * 8;
    const int ar1 = s1 >> 2, ac1 = (s1 & 3) * 8;
    int ir0 = i0 + ar0; if (ir0 > nloc - 1) ir0 = nloc - 1;
    int ir1 = i0 + ar1; if (ir1 > nloc - 1) ir1 = nloc - 1;
    int jr0 = j0 + ar0; if (jr0 > NM1_ - 1) jr0 = NM1_ - 1;
    int jr1 = j0 + ar1; if (jr1 > NM1_ - 1) jr1 = NM1_ - 1;
    const unsigned short* a0 = AF + (size_t)ir0 * D_ + ac0;
    const unsigned short* a1 = AF + (size_t)ir1 * D_ + ac1;
    const unsigned short* b0 = attw + (size_t)jr0 * D_ + ac0;
    const unsigned short* b1 = attw + (size_t)jr1 * D_ + ac1;

    for (int k0 = 0; k0 < D_; k0 += 32) {
        GLD16(a0 + k0, As + s0 * 8);
        GLD16(a1 + k0, As + s1 * 8);
        GLD16(b0 + k0, Bs + s0 * 8);
        GLD16(b1 + k0, Bs + s1 * 8);
        __syncthreads();
        bf16x8 a[4], bb[4];
#pragma unroll
        for (int m = 0; m < 4; ++m)
            a[m] = *(const bf16x8*)(As + (wr * 64 + m * 16 + l15) * 32 + hi8);
#pragma unroll
        for (int n = 0; n < 4; ++n)
            bb[n] = *(const bf16x8*)(Bs + (wc * 64 + n * 16 + l15) * 32 + hi8);
#pragma unroll
        for (int m = 0; m < 4; ++m)
#pragma unroll
            for (int n = 0; n < 4; ++n)
                acc[m][n] = __builtin_amdgcn_mfma_f32_16x16x32_bf16(a[m], bb[n], acc[m][n], 0, 0, 0);
        __syncthreads();
    }

#pragma unroll
    for (int m = 0; m < 4; ++m) {
        int ib = i0 + wr * 64 + m * 16 + (lane >> 4) * 4;
#pragma unroll
        for (int n = 0; n < 4; ++n) {
            int j = j0 + wc * 64 + n * 16 + l15;
            if (j < NM1_) {
                float bias = bf2f(attb[j]);
#pragma unroll
                for (int q = 0; q < 4; ++q) {
                    int ii = ib + q;
                    if (ii < nloc) {
                        int r = ii % N_;
                        int c = j + (j >= r);
                        Mbuf[(size_t)(row_base + ii) * N_ + c] = acc[m][n][q] + bias;
                    }
                }
            }
        }
    }
}

// ---------------- K3b: f32 row softmax, float4 vectorized (diag -> exact 0)
__global__ __launch_bounds__(256) void k_softmax(float* __restrict__ Mbuf, int row_base) {
    const int i = row_base + blockIdx.x;
    const int r = i % N_;
    float4* row = (float4*)(Mbuf + (size_t)i * N_);
    const int t = threadIdx.x;
    float4 f[3];
#pragma unroll
    for (int q = 0; q < 3; ++q) {
        int c4 = t + 256 * q;
        if (c4 < N_ / 4) f[q] = row[c4];
        else { f[q].x = -1e30f; f[q].y = -1e30f; f[q].z = -1e30f; f[q].w = -1e30f; }
        int b = c4 * 4;
        if (b + 0 == r) f[q].x = -1e30f;
        if (b + 1 == r) f[q].y = -1e30f;
        if (b + 2 == r) f[q].z = -1e30f;
        if (b + 3 == r) f[q].w = -1e30f;
    }
    float m = -1e30f;
#pragma unroll
    for (int q = 0; q < 3; ++q)
        m = fmaxf(m, fmaxf(fmaxf(f[q].x, f[q].y), fmaxf(f[q].z, f[q].w)));
#pragma unroll
    for (int off = 32; off >= 1; off >>= 1) m = fmaxf(m, __shfl_xor(m, off, 64));
    __shared__ float red[4];
    if ((t & 63) == 0) red[t >> 6] = m;
    __syncthreads();
    m = fmaxf(fmaxf(red[0], red[1]), fmaxf(red[2], red[3]));

    float s = 0.f;
#pragma unroll
    for (int q = 0; q < 3; ++q) {
        f[q].x = __expf(f[q].x - m); f[q].y = __expf(f[q].y - m);
        f[q].z = __expf(f[q].z - m); f[q].w = __expf(f[q].w - m);
        s += f[q].x + f[q].y + f[q].z + f[q].w;
    }
#pragma unroll
    for (int off = 32; off >= 1; off >>= 1) s += __shfl_xor(s, off, 64);
    __shared__ float red2[4];
    if ((t & 63) == 0) red2[t >> 6] = s;
    __syncthreads();
    s = red2[0] + red2[1] + red2[2] + red2[3];
    float inv = 1.0f / s;
#pragma unroll
    for (int q = 0; q < 3; ++q) {
        int c4 = t + 256 * q;
        if (c4 < N_ / 4) {
            float4 o; o.x = f[q].x * inv; o.y = f[q].y * inv;
            o.z = f[q].z * inv; o.w = f[q].w * inv;
            row[c4] = o;
        }
    }
}

// ---------------- K4: MFMA att_feat = M(f32) @ AF; A reg-staged f32->bf16, B via GLD16
__global__ __launch_bounds__(256) void k_attgemm(const float* __restrict__ Mbuf,
                                                 const unsigned short* __restrict__ AFT,
                                                 unsigned short* __restrict__ ATF,
                                                 int batch_base) {
    __shared__ __bf16 As[128 * 32];
    __shared__ __bf16 Bs[128 * 32];
    const int t = threadIdx.x;
    const int jt = blockIdx.x, it = blockIdx.y, bl = blockIdx.z;
    const int bg = batch_base + bl;
    const int i0 = it * 128, j0 = jt * 128;
    const int lane = t & 63, wv = t >> 6;
    const int wr = wv >> 1, wc = wv & 1;
    const int l15 = lane & 15, hi8 = (lane >> 4) * 8;

    f32x4 zero = {0.f, 0.f, 0.f, 0.f};
    f32x4 acc[4][4];
#pragma unroll
    for (int m = 0; m < 4; ++m)
#pragma unroll
        for (int n = 0; n < 4; ++n) acc[m][n] = zero;

    const int s0 = t, s1 = t + 256;
    int ir0 = i0 + (s0 >> 2); if (ir0 > N_ - 1) ir0 = N_ - 1;
    int ir1 = i0 + (s1 >> 2); if (ir1 > N_ - 1) ir1 = N_ - 1;
    int jr0 = j0 + (s0 >> 2); if (jr0 > D_ - 1) jr0 = D_ - 1;
    int jr1 = j0 + (s1 >> 2); if (jr1 > D_ - 1) jr1 = D_ - 1;
    const int ac0 = (s0 & 3) * 8, ac1 = (s1 & 3) * 8;
    const float* a0 = Mbuf + (size_t)(bg * N_ + ir0) * N_ + ac0;
    const float* a1 = Mbuf + (size_t)(bg * N_ + ir1) * N_ + ac1;
    const unsigned short* b0 = AFT + (size_t)(bl * D_ + jr0) * N_ + ac0;
    const unsigned short* b1 = AFT + (size_t)(bl * D_ + jr1) * N_ + ac1;

    for (int k0 = 0; k0 < N_; k0 += 32) {        // 87 iterations exact
        GLD16(b0 + k0, Bs + s0 * 8);
        GLD16(b1 + k0, Bs + s1 * 8);
        float4 u0 = *(const float4*)(a0 + k0);
        float4 u1 = *(const float4*)(a0 + k0 + 4);
        float4 v0 = *(const float4*)(a1 + k0);
        float4 v1 = *(const float4*)(a1 + k0 + 4);
        union { unsigned short u[8]; bf16x8 v; } w0, w1;
        w0.u[0] = f2bf(u0.x); w0.u[1] = f2bf(u0.y); w0.u[2] = f2bf(u0.z); w0.u[3] = f2bf(u0.w);
        w0.u[4] = f2bf(u1.x); w0.u[5] = f2bf(u1.y); w0.u[6] = f2bf(u1.z); w0.u[7] = f2bf(u1.w);
        w1.u[0] = f2bf(v0.x); w1.u[1] = f2bf(v0.y); w1.u[2] = f2bf(v0.z); w1.u[3] = f2bf(v0.w);
        w1.u[4] = f2bf(v1.x); w1.u[5] = f2bf(v1.y); w1.u[6] = f2bf(v1.z); w1.u[7] = f2bf(v1.w);
        *(bf16x8*)(As + s0 * 8) = w0.v;
        *(bf16x8*)(As + s1 * 8) = w1.v;
        __syncthreads();
        bf16x8 a[4], bb[4];
#pragma unroll
        for (int m = 0; m < 4; ++m)
            a[m] = *(const bf16x8*)(As + (wr * 64 + m * 16 + l15) * 32 + hi8);
#pragma unroll
        for (int n = 0; n < 4; ++n)
            bb[n] = *(const bf16x8*)(Bs + (wc * 64 + n * 16 + l15) * 32 + hi8);
#pragma unroll
        for (int m = 0; m < 4; ++m)
#pragma unroll
            for (int n = 0; n < 4; ++n)
                acc[m][n] = __builtin_amdgcn_mfma_f32_16x16x32_bf16(a[m], bb[n], acc[m][n], 0, 0, 0);
        __syncthreads();
    }

#pragma unroll
    for (int m = 0; m < 4; ++m) {
        int rb = i0 + wr * 64 + m * 16 + (lane >> 4) * 4;
#pragma unroll
        for (int n = 0; n < 4; ++n) {
            int d = j0 + wc * 64 + n * 16 + l15;
            if (d < D_) {
#pragma unroll
                for (int q = 0; q < 4; ++q) {
                    int rr = rb + q;
                    if (rr < N_)
                        ATF[((size_t)(bl * N_ + rr)) * D_ + d] = f2bf(acc[m][n][q]);
                }
            }
        }
    }
}

// ---------------- K5: MFMA heads + fused props epilogue (f32 out)
__global__ __launch_bounds__(256) void k_head(const unsigned short* __restrict__ ATF,
                                              const unsigned short* __restrict__ AF,
                                              const unsigned short* __restrict__ clsw,
                                              const unsigned short* __restrict__ clsb,
                                              const unsigned short* __restrict__ regw,
                                              const unsigned short* __restrict__ regb,
                                              const unsigned short* __restrict__ anch,
                                              float* __restrict__ props,
                                              int row_base, int nloc) {
    __shared__ __bf16 As[128 * 32];
    __shared__ __bf16 Ws[80 * 32];
    const int t = threadIdx.x;
    const int i0 = blockIdx.x * 128;
    const int lane = t & 63, wv = t >> 6;
    const int l15 = lane & 15, hi8 = (lane >> 4) * 8;

    f32x4 zero = {0.f, 0.f, 0.f, 0.f};
    f32x4 acc[2][5];
#pragma unroll
    for (int m = 0; m < 2; ++m)
#pragma unroll
        for (int n = 0; n < 5; ++n) acc[m][n] = zero;

    const int s0 = t, s1 = t + 256;
    const int ar0 = s0 >> 2, ac0 = (s0 & 3) * 8;
    const int ar1 = s1 >> 2, ac1 = (s1 & 3) * 8;
    int ir0 = i0 + ar0; if (ir0 > nloc - 1) ir0 = nloc - 1;
    int ir1 = i0 + ar1; if (ir1 > nloc - 1) ir1 = nloc - 1;
    const unsigned short* w0base = (ar0 < 2) ? (clsw + (size_t)ar0 * D2_)
                                             : (regw + (size_t)(ar0 - 2) * D2_);
    int r1 = 64 + (t >> 2);
    int rc = r1 < 75 ? r1 : 74;
    const unsigned short* w1base = regw + (size_t)(rc - 2) * D2_;
    const int w1c = (t & 3) * 8;

    for (int p = 0; p < 2; ++p) {
        const unsigned short* Asrc = (p == 0) ? ATF : AF;
        const int wcol = p * D_;
        for (int k0 = 0; k0 < D_; k0 += 32) {
            GLD16(Asrc + (size_t)ir0 * D_ + ac0 + k0, As + s0 * 8);
            GLD16(Asrc + (size_t)ir1 * D_ + ac1 + k0, As + s1 * 8);
            GLD16(w0base + wcol + k0 + ac0, Ws + s0 * 8);
            if (t < 64) GLD16(w1base + wcol + k0 + w1c, Ws + (size_t)(256 + t) * 8);
            __syncthreads();
            bf16x8 a[2], bb[5];
#pragma unroll
            for (int m = 0; m < 2; ++m)
                a[m] = *(const bf16x8*)(As + (wv * 32 + m * 16 + l15) * 32 + hi8);
#pragma unroll
            for (int n = 0; n < 5; ++n)
                bb[n] = *(const bf16x8*)(Ws + (n * 16 + l15) * 32 + hi8);
#pragma unroll
            for (int m = 0; m < 2; ++m)
#pragma unroll
                for (int n = 0; n < 5; ++n)
                    acc[m][n] = __builtin_amdgcn_mfma_f32_16x16x32_bf16(a[m], bb[n], acc[m][n], 0, 0, 0);
            __syncthreads();
        }
    }

#pragma unroll
    for (int m = 0; m < 2; ++m) {
        int ib = i0 + wv * 32 + m * 16 + (lane >> 4) * 4;
#pragma unroll
        for (int n = 0; n < 5; ++n) {
            int j = n * 16 + l15;
            if (j < 75) {
#pragma unroll
                for (int q = 0; q < 4; ++q) {
                    int i = ib + q;
                    if (i < nloc) {
                        size_t g = (size_t)(row_base + i);
                        int nn = i % N_;
                        float v = acc[m][n][q];
                        if (j < 2) {
                            props[g * PW_ + j] = v + bf2f(clsb[j]);
                            props[g * PW_ + 2 + j] = bf2f(anch[(size_t)nn * PW_ + 2 + j]);
                        } else {
                            int tt = j - 2;
                            props[g * PW_ + 4 + tt] = v + bf2f(regb[tt]) + bf2f(anch[(size_t)nn * PW_ + 4 + tt]);
                        }
                    }
                }
            }
        }
    }
}

extern "C" void kernel_launch(void* const* d_in, const int* in_sizes, int n_in,
                              void* d_out, int out_size, void* d_ws, size_t ws_size,
                              hipStream_t stream) {
    (void)in_sizes; (void)n_in; (void)out_size;

    float* props = (float*)d_out;
    float* Mbuf  = props + (size_t)ROWS_ * PW_;

    char* ws = (char*)d_ws;
    int* flags = (int*)(ws + OFF_FLAGS);
    float* feat = (float*)(ws + OFF_FEAT);
    char* canon = ws + OFF_CANON;
    unsigned short* cx    = (unsigned short*)(canon + C_X);
    unsigned short* cattw = (unsigned short*)(canon + C_ATTW);
    unsigned short* ccw   = (unsigned short*)(canon + C_CW);
    unsigned short* canch = (unsigned short*)(canon + C_ANCH);
    unsigned short* cclsw = (unsigned short*)(canon + C_CLSW);
    unsigned short* cregw = (unsigned short*)(canon + C_REGW);
    unsigned short* ccb   = (unsigned short*)(canon + C_CB);
    unsigned short* cattb = (unsigned short*)(canon + C_ATTB);
    unsigned short* cclsb = (unsigned short*)(canon + C_CLSB);
    unsigned short* cregb = (unsigned short*)(canon + C_REGB);
    int* ccut = (int*)(canon + C_CUT);
    int* cmsk = (int*)(canon + C_MASK);

    size_t base = (size_t)(12u << 20);
    size_t sa16 = (size_t)16 * N_ * D_ * 2;
    size_t sa4  = (size_t)4  * N_ * D_ * 2;
    int CN = (ws_size >= base + 3 * sa16) ? 16 : (ws_size >= base + 3 * sa4) ? 4 : 1;
    size_t SA = (size_t)CN * N_ * D_ * 2;
    unsigned short* AF  = (unsigned short*)(ws + base);
    unsigned short* AFT = (unsigned short*)(ws + base + SA);
    unsigned short* ATF = (unsigned short*)(ws + base + 2 * SA);

    k_detect<<<dim3(1), dim3(256), 0, stream>>>((const unsigned int*)d_in[3],
                                                (const unsigned int*)d_in[10],
                                                (const unsigned int*)d_in[11], flags);
    k_canon_f<<<dim3(1024), dim3(256), 0, stream>>>(d_in[0], d_in[1], d_in[2], d_in[3], d_in[4],
                                                    d_in[5], d_in[6], d_in[7], d_in[8], d_in[9],
                                                    canon, flags);
    k_canon_i<<<dim3(120), dim3(256), 0, stream>>>(d_in[10], d_in[11], canon, flags);
    k_conv<<<dim3(880), dim3(256), 0, stream>>>(cx, ccw, ccb, feat);

    const int nchunk = 16 / CN;
    for (int c = 0; c < nchunk; ++c) {
        const int bb = c * CN;
        const int rb = bb * N_;
        const int nl = CN * N_;
        const int it128 = (nl + 127) / 128;
        k_gather_af<<<dim3(N_, CN), dim3(256), 0, stream>>>(feat, ccut, cmsk, AF, bb);
        k_gather_aft<<<dim3(D_, CN), dim3(256), 0, stream>>>(feat, ccut, cmsk, AFT, bb);
        k_scores<<<dim3(22, it128), dim3(256), 0, stream>>>(AF, cattw, cattb, Mbuf, rb, nl);
        k_softmax<<<dim3(nl), dim3(256), 0, stream>>>(Mbuf, rb);
        k_attgemm<<<dim3(6, 22, CN), dim3(256), 0, stream>>>(Mbuf, AFT, ATF, bb);
        k_head<<<dim3(it128), dim3(256), 0, stream>>>(ATF, AF, cclsw, cclsb, cregw, cregb,
                                                      canch, props, rb, nl);
    }
}

// Round 6
// 1211.981 us; speedup vs baseline: 18.2812x; 1.0474x over previous
//
#include <hip/hip_runtime.h>

#define B_    16
#define CIN_  512
#define CF_   64
#define FH_   11
#define FW_   20
#define N_    2784
#define NM1_  2783
#define D_    704
#define D2_   1408
#define ROWS_ 44544
#define PW_   77

// ---- input element counts
#define NX_     1802240
#define NCW_    32768
#define NCB_    64
#define NATTW_  1959232
#define NATTB_  2783
#define NCLSW_  2816
#define NCLSB_  2
#define NREGW_  102784
#define NREGB_  73
#define NANCH_  214368
#define NCUT_   30624

// ---- canonical ws layout (byte offsets)
#define OFF_FLAGS   0u
#define OFF_FEAT    256u
#define OFF_CANON   (1u<<20)
#define C_X      0u
#define C_ATTW   3604480u
#define C_CW     7522944u
#define C_ANCH   7588480u
#define C_CLSW   8017216u
#define C_REGW   8022848u
#define C_CB     8228416u
#define C_ATTB   8228544u
#define C_CLSB   8234112u
#define C_REGB   8234128u
#define C_CUT    8234288u
#define C_MASK   8356784u

typedef __bf16 bf16x8 __attribute__((ext_vector_type(8)));
typedef float  f32x4  __attribute__((ext_vector_type(4)));

typedef __attribute__((address_space(1))) void g_void;
typedef __attribute__((address_space(3))) void l_void;
#define GLD16(gp, lp) __builtin_amdgcn_global_load_lds((g_void*)(gp), (l_void*)(lp), 16, 0, 0)

__device__ __forceinline__ float bf2f(unsigned short u) {
    union { unsigned int u; float f; } v; v.u = ((unsigned int)u) << 16; return v.f;
}
__device__ __forceinline__ unsigned short f2bf(float f) {
    union { float f; unsigned int u; } v; v.f = f;
    unsigned int x = v.u;
    return (unsigned short)((x + 0x7FFFu + ((x >> 16) & 1u)) >> 16);
}

// ---------------- K0: dtype detection (deterministic, input-only)
__global__ __launch_bounds__(256) void k_detect(const unsigned int* __restrict__ attw,
                                                const unsigned int* __restrict__ cut,
                                                const unsigned int* __restrict__ msk,
                                                int* __restrict__ flags) {
    __shared__ int cnt[3];
    int t = threadIdx.x;
    if (t < 3) cnt[t] = 0;
    __syncthreads();
    int c0 = 0, c1 = 0, c2 = 0;
    for (int i = t; i < 2048; i += 256) {
        unsigned int e = (attw[i] >> 7) & 0xFFu;
        if (e >= 127u) c0++;
    }
    for (int i = t; i < 4096; i += 256) if (cut[i] >= 32u) c1++;
    for (int i = t; i < 4096; i += 256) if (msk[i] >= 2u)  c2++;
    atomicAdd(&cnt[0], c0); atomicAdd(&cnt[1], c1); atomicAdd(&cnt[2], c2);
    __syncthreads();
    if (t == 0) {
        flags[0] = cnt[0] > 64;
        flags[1] = cnt[1] > 64;
        flags[2] = cnt[2] > 64;
        flags[3] = 0;
    }
}

// ---------------- K0b: canonicalize all float inputs to bf16
__device__ __forceinline__ void cvt_arr(const void* s, unsigned short* d, int n, int isf32,
                                        int tid, int stride) {
    if (isf32) {
        const float* p = (const float*)s;
        for (int i = tid; i < n; i += stride) d[i] = f2bf(p[i]);
    } else {
        const unsigned short* p = (const unsigned short*)s;
        for (int i = tid; i < n; i += stride) d[i] = p[i];
    }
}

__global__ __launch_bounds__(256) void k_canon_f(const void* sx, const void* scw, const void* scb,
                                                 const void* sattw, const void* sattb,
                                                 const void* sclsw, const void* sclsb,
                                                 const void* sregw, const void* sregb,
                                                 const void* sanch, char* canon,
                                                 const int* __restrict__ flags) {
    const int isf32 = flags[0];
    const int tid = blockIdx.x * 256 + threadIdx.x;
    const int stride = gridDim.x * 256;
    cvt_arr(sx,    (unsigned short*)(canon + C_X),    NX_,    isf32, tid, stride);
    cvt_arr(sattw, (unsigned short*)(canon + C_ATTW), NATTW_, isf32, tid, stride);
    cvt_arr(scw,   (unsigned short*)(canon + C_CW),   NCW_,   isf32, tid, stride);
    cvt_arr(sanch, (unsigned short*)(canon + C_ANCH), NANCH_, isf32, tid, stride);
    cvt_arr(sclsw, (unsigned short*)(canon + C_CLSW), NCLSW_, isf32, tid, stride);
    cvt_arr(sregw, (unsigned short*)(canon + C_REGW), NREGW_, isf32, tid, stride);
    cvt_arr(scb,   (unsigned short*)(canon + C_CB),   NCB_,   isf32, tid, stride);
    cvt_arr(sattb, (unsigned short*)(canon + C_ATTB), NATTB_, isf32, tid, stride);
    cvt_arr(sclsb, (unsigned short*)(canon + C_CLSB), NCLSB_, isf32, tid, stride);
    cvt_arr(sregb, (unsigned short*)(canon + C_REGB), NREGB_, isf32, tid, stride);
}

// ---------------- K0c: canonicalize int inputs to int32
__global__ __launch_bounds__(256) void k_canon_i(const void* scut, const void* smsk,
                                                 char* canon, const int* __restrict__ flags) {
    const int cutb = flags[1], mskb = flags[2];
    int* ccut = (int*)(canon + C_CUT);
    int* cmsk = (int*)(canon + C_MASK);
    const int tid = blockIdx.x * 256 + threadIdx.x;
    const int stride = gridDim.x * 256;
    for (int i = tid; i < NCUT_; i += stride) {
        ccut[i] = cutb ? (int)((const unsigned char*)scut)[i] : ((const int*)scut)[i];
        int m = mskb ? (int)((const unsigned char*)smsk)[i] : ((const int*)smsk)[i];
        cmsk[i] = (m != 0);
    }
}

// ---------------- K1: 1x1 conv
__global__ __launch_bounds__(256) void k_conv(const unsigned short* __restrict__ x,
                                              const unsigned short* __restrict__ cw,
                                              const unsigned short* __restrict__ cb,
                                              float* __restrict__ feat) {
    int idx = blockIdx.x * 256 + threadIdx.x;           // 880*256 = 225280 exact
    int w = idx % FW_;
    int h = (idx / FW_) % FH_;
    int o = (idx / (FW_ * FH_)) % CF_;
    int b = idx / (FW_ * FH_ * CF_);
    const unsigned short* xp = x + ((size_t)(b * CIN_) * FH_ + h) * FW_ + w;
    const unsigned short* wp = cw + (size_t)o * CIN_;
    float acc = bf2f(cb[o]);
#pragma unroll 8
    for (int c = 0; c < CIN_; ++c)
        acc += bf2f(xp[(size_t)c * (FH_ * FW_)]) * bf2f(wp[c]);
    feat[idx] = acc;
}

// ---------------- K2a: AF chunk
__global__ __launch_bounds__(256) void k_gather_af(const float* __restrict__ feat,
                                                   const int* __restrict__ cut,
                                                   const int* __restrict__ inv,
                                                   unsigned short* __restrict__ AF,
                                                   int batch_base) {
    int n = blockIdx.x, bl = blockIdx.y;
    int b = batch_base + bl;
    __shared__ int cu[FH_];
    __shared__ int iv[FH_];
    int t = threadIdx.x;
    if (t < FH_) { cu[t] = cut[n * FH_ + t]; iv[t] = inv[n * FH_ + t]; }
    __syncthreads();
    unsigned short* out = AF + ((size_t)(bl * N_ + n)) * D_;
    for (int d = t; d < D_; d += 256) {
        int c = d / FH_, h = d - c * FH_;
        float v = iv[h] ? 0.f : feat[((b * CF_ + c) * FH_ + h) * FW_ + cu[h]];
        out[d] = f2bf(v);
    }
}

// ---------------- K2b: AFT chunk
__global__ __launch_bounds__(256) void k_gather_aft(const float* __restrict__ feat,
                                                    const int* __restrict__ cut,
                                                    const int* __restrict__ inv,
                                                    unsigned short* __restrict__ AFT,
                                                    int batch_base) {
    int d = blockIdx.x, bl = blockIdx.y;
    int b = batch_base + bl;
    int c = d / FH_, h = d - c * FH_;
    const float* fp = feat + ((b * CF_ + c) * FH_ + h) * FW_;
    unsigned short* out = AFT + ((size_t)(bl * D_ + d)) * N_;
    for (int n = threadIdx.x; n < N_; n += 256) {
        int w = cut[n * FH_ + h];
        float v = inv[n * FH_ + h] ? 0.f : fp[w];
        out[n] = f2bf(v);
    }
}

// ---------------- K3a: MFMA scores GEMM, shifted-scatter into M (f32)
__global__ __launch_bounds__(256) void k_scores(const unsigned short* __restrict__ AF,
                                                const unsigned short* __restrict__ attw,
                                                const unsigned short* __restrict__ attb,
                                                float* __restrict__ Mbuf,
                                                int row_base, int nloc) {
    __shared__ __bf16 As[128 * 32];
    __shared__ __bf16 Bs[128 * 32];
    const int t = threadIdx.x;
    const int jt = blockIdx.x, it = blockIdx.y;
    const int i0 = it * 128, j0 = jt * 128;
    const int lane = t & 63, wv = t >> 6;
    const int wr = wv >> 1, wc = wv & 1;
    const int l15 = lane & 15, hi8 = (lane >> 4) * 8;

    f32x4 zero = {0.f, 0.f, 0.f, 0.f};
    f32x4 acc[4][4];
#pragma unroll
    for (int m = 0; m < 4; ++m)
#pragma unroll
        for (int n = 0; n < 4; ++n) acc[m][n] = zero;

    const int s0 = t, s1 = t + 256;
    const int ar0 = s0 >> 2, ac0 = (s0 & 3) * 8;
    const int ar1 = s1 >> 2, ac1 = (s1 & 3) * 8;
    int ir0 = i0 + ar0; if (ir0 > nloc - 1) ir0 = nloc - 1;
    int ir1 = i0 + ar1; if (ir1 > nloc - 1) ir1 = nloc - 1;
    int jr0 = j0 + ar0; if (jr0 > NM1_ - 1) jr0 = NM1_ - 1;
    int jr1 = j0 + ar1; if (jr1 > NM1_ - 1) jr1 = NM1_ - 1;
    const unsigned short* a0 = AF + (size_t)ir0 * D_ + ac0;
    const unsigned short* a1 = AF + (size_t)ir1 * D_ + ac1;
    const unsigned short* b0 = attw + (size_t)jr0 * D_ + ac0;
    const unsigned short* b1 = attw + (size_t)jr1 * D_ + ac1;

    for (int k0 = 0; k0 < D_; k0 += 32) {
        GLD16(a0 + k0, As + s0 * 8);
        GLD16(a1 + k0, As + s1 * 8);
        GLD16(b0 + k0, Bs + s0 * 8);
        GLD16(b1 + k0, Bs + s1 * 8);
        __syncthreads();
        bf16x8 a[4], bb[4];
#pragma unroll
        for (int m = 0; m < 4; ++m)
            a[m] = *(const bf16x8*)(As + (wr * 64 + m * 16 + l15) * 32 + hi8);
#pragma unroll
        for (int n = 0; n < 4; ++n)
            bb[n] = *(const bf16x8*)(Bs + (wc * 64 + n * 16 + l15) * 32 + hi8);
#pragma unroll
        for (int m = 0; m < 4; ++m)
#pragma unroll
            for (int n = 0; n < 4; ++n)
                acc[m][n] = __builtin_amdgcn_mfma_f32_16x16x32_bf16(a[m], bb[n], acc[m][n], 0, 0, 0);
        __syncthreads();
    }

#pragma unroll
    for (int m = 0; m < 4; ++m) {
        int ib = i0 + wr * 64 + m * 16 + (lane >> 4) * 4;
#pragma unroll
        for (int n = 0; n < 4; ++n) {
            int j = j0 + wc * 64 + n * 16 + l15;
            if (j < NM1_) {
                float bias = bf2f(attb[j]);
#pragma unroll
                for (int q = 0; q < 4; ++q) {
                    int ii = ib + q;
                    if (ii < nloc) {
                        int r = ii % N_;
                        int c = j + (j >= r);
                        Mbuf[(size_t)(row_base + ii) * N_ + c] = acc[m][n][q] + bias;
                    }
                }
            }
        }
    }
}

// ---------------- K3b: f32 row softmax, dual-write f32 M (d_out) + bf16 shadow (ws)
__global__ __launch_bounds__(256) void k_softmax(float* __restrict__ Mbuf,
                                                 unsigned short* __restrict__ Mbf,
                                                 int row_base) {
    const int il = blockIdx.x;
    const int i = row_base + il;
    const int r = i % N_;
    float4* row = (float4*)(Mbuf + (size_t)i * N_);
    unsigned short* orow = Mbf + (size_t)il * N_;
    const int t = threadIdx.x;
    float4 f[3];
#pragma unroll
    for (int q = 0; q < 3; ++q) {
        int c4 = t + 256 * q;
        if (c4 < N_ / 4) f[q] = row[c4];
        else { f[q].x = -1e30f; f[q].y = -1e30f; f[q].z = -1e30f; f[q].w = -1e30f; }
        int b = c4 * 4;
        if (b + 0 == r) f[q].x = -1e30f;
        if (b + 1 == r) f[q].y = -1e30f;
        if (b + 2 == r) f[q].z = -1e30f;
        if (b + 3 == r) f[q].w = -1e30f;
    }
    float m = -1e30f;
#pragma unroll
    for (int q = 0; q < 3; ++q)
        m = fmaxf(m, fmaxf(fmaxf(f[q].x, f[q].y), fmaxf(f[q].z, f[q].w)));
#pragma unroll
    for (int off = 32; off >= 1; off >>= 1) m = fmaxf(m, __shfl_xor(m, off, 64));
    __shared__ float red[4];
    if ((t & 63) == 0) red[t >> 6] = m;
    __syncthreads();
    m = fmaxf(fmaxf(red[0], red[1]), fmaxf(red[2], red[3]));

    float s = 0.f;
#pragma unroll
    for (int q = 0; q < 3; ++q) {
        f[q].x = __expf(f[q].x - m); f[q].y = __expf(f[q].y - m);
        f[q].z = __expf(f[q].z - m); f[q].w = __expf(f[q].w - m);
        s += f[q].x + f[q].y + f[q].z + f[q].w;
    }
#pragma unroll
    for (int off = 32; off >= 1; off >>= 1) s += __shfl_xor(s, off, 64);
    __shared__ float red2[4];
    if ((t & 63) == 0) red2[t >> 6] = s;
    __syncthreads();
    s = red2[0] + red2[1] + red2[2] + red2[3];
    float inv = 1.0f / s;
#pragma unroll
    for (int q = 0; q < 3; ++q) {
        int c4 = t + 256 * q;
        if (c4 < N_ / 4) {
            float4 o; o.x = f[q].x * inv; o.y = f[q].y * inv;
            o.z = f[q].z * inv; o.w = f[q].w * inv;
            row[c4] = o;
            union { unsigned short u[4]; uint2 v; } p;
            p.u[0] = f2bf(o.x); p.u[1] = f2bf(o.y);
            p.u[2] = f2bf(o.z); p.u[3] = f2bf(o.w);
            *(uint2*)(orow + c4 * 4) = p.v;
        }
    }
}

// ---------------- K4: MFMA att_feat = Mbf(bf16) @ AF; both operands via GLD16
__global__ __launch_bounds__(256) void k_attgemm(const unsigned short* __restrict__ Mbf,
                                                 const unsigned short* __restrict__ AFT,
                                                 unsigned short* __restrict__ ATF) {
    __shared__ __bf16 As[128 * 32];
    __shared__ __bf16 Bs[128 * 32];
    const int t = threadIdx.x;
    const int jt = blockIdx.x, it = blockIdx.y, bl = blockIdx.z;
    const int i0 = it * 128, j0 = jt * 128;
    const int lane = t & 63, wv = t >> 6;
    const int wr = wv >> 1, wc = wv & 1;
    const int l15 = lane & 15, hi8 = (lane >> 4) * 8;

    f32x4 zero = {0.f, 0.f, 0.f, 0.f};
    f32x4 acc[4][4];
#pragma unroll
    for (int m = 0; m < 4; ++m)
#pragma unroll
        for (int n = 0; n < 4; ++n) acc[m][n] = zero;

    const int s0 = t, s1 = t + 256;
    int ir0 = i0 + (s0 >> 2); if (ir0 > N_ - 1) ir0 = N_ - 1;
    int ir1 = i0 + (s1 >> 2); if (ir1 > N_ - 1) ir1 = N_ - 1;
    int jr0 = j0 + (s0 >> 2); if (jr0 > D_ - 1) jr0 = D_ - 1;
    int jr1 = j0 + (s1 >> 2); if (jr1 > D_ - 1) jr1 = D_ - 1;
    const int ac0 = (s0 & 3) * 8, ac1 = (s1 & 3) * 8;
    const unsigned short* a0 = Mbf + ((size_t)bl * N_ + ir0) * N_ + ac0;
    const unsigned short* a1 = Mbf + ((size_t)bl * N_ + ir1) * N_ + ac1;
    const unsigned short* b0 = AFT + (size_t)(bl * D_ + jr0) * N_ + ac0;
    const unsigned short* b1 = AFT + (size_t)(bl * D_ + jr1) * N_ + ac1;

    for (int k0 = 0; k0 < N_; k0 += 32) {        // 87 iterations exact
        GLD16(a0 + k0, As + s0 * 8);
        GLD16(a1 + k0, As + s1 * 8);
        GLD16(b0 + k0, Bs + s0 * 8);
        GLD16(b1 + k0, Bs + s1 * 8);
        __syncthreads();
        bf16x8 a[4], bb[4];
#pragma unroll
        for (int m = 0; m < 4; ++m)
            a[m] = *(const bf16x8*)(As + (wr * 64 + m * 16 + l15) * 32 + hi8);
#pragma unroll
        for (int n = 0; n < 4; ++n)
            bb[n] = *(const bf16x8*)(Bs + (wc * 64 + n * 16 + l15) * 32 + hi8);
#pragma unroll
        for (int m = 0; m < 4; ++m)
#pragma unroll
            for (int n = 0; n < 4; ++n)
                acc[m][n] = __builtin_amdgcn_mfma_f32_16x16x32_bf16(a[m], bb[n], acc[m][n], 0, 0, 0);
        __syncthreads();
    }

#pragma unroll
    for (int m = 0; m < 4; ++m) {
        int rb = i0 + wr * 64 + m * 16 + (lane >> 4) * 4;
#pragma unroll
        for (int n = 0; n < 4; ++n) {
            int d = j0 + wc * 64 + n * 16 + l15;
            if (d < D_) {
#pragma unroll
                for (int q = 0; q < 4; ++q) {
                    int rr = rb + q;
                    if (rr < N_)
                        ATF[((size_t)(bl * N_ + rr)) * D_ + d] = f2bf(acc[m][n][q]);
                }
            }
        }
    }
}

// ---------------- K5: MFMA heads + fused props epilogue (f32 out)
__global__ __launch_bounds__(256) void k_head(const unsigned short* __restrict__ ATF,
                                              const unsigned short* __restrict__ AF,
                                              const unsigned short* __restrict__ clsw,
                                              const unsigned short* __restrict__ clsb,
                                              const unsigned short* __restrict__ regw,
                                              const unsigned short* __restrict__ regb,
                                              const unsigned short* __restrict__ anch,
                                              float* __restrict__ props,
                                              int row_base, int nloc) {
    __shared__ __bf16 As[128 * 32];
    __shared__ __bf16 Ws[80 * 32];
    const int t = threadIdx.x;
    const int i0 = blockIdx.x * 128;
    const int lane = t & 63, wv = t >> 6;
    const int l15 = lane & 15, hi8 = (lane >> 4) * 8;

    f32x4 zero = {0.f, 0.f, 0.f, 0.f};
    f32x4 acc[2][5];
#pragma unroll
    for (int m = 0; m < 2; ++m)
#pragma unroll
        for (int n = 0; n < 5; ++n) acc[m][n] = zero;

    const int s0 = t, s1 = t + 256;
    const int ar0 = s0 >> 2, ac0 = (s0 & 3) * 8;
    const int ar1 = s1 >> 2, ac1 = (s1 & 3) * 8;
    int ir0 = i0 + ar0; if (ir0 > nloc - 1) ir0 = nloc - 1;
    int ir1 = i0 + ar1; if (ir1 > nloc - 1) ir1 = nloc - 1;
    const unsigned short* w0base = (ar0 < 2) ? (clsw + (size_t)ar0 * D2_)
                                             : (regw + (size_t)(ar0 - 2) * D2_);
    int r1 = 64 + (t >> 2);
    int rc = r1 < 75 ? r1 : 74;
    const unsigned short* w1base = regw + (size_t)(rc - 2) * D2_;
    const int w1c = (t & 3) * 8;

    for (int p = 0; p < 2; ++p) {
        const unsigned short* Asrc = (p == 0) ? ATF : AF;
        const int wcol = p * D_;
        for (int k0 = 0; k0 < D_; k0 += 32) {
            GLD16(Asrc + (size_t)ir0 * D_ + ac0 + k0, As + s0 * 8);
            GLD16(Asrc + (size_t)ir1 * D_ + ac1 + k0, As + s1 * 8);
            GLD16(w0base + wcol + k0 + ac0, Ws + s0 * 8);
            if (t < 64) GLD16(w1base + wcol + k0 + w1c, Ws + (size_t)(256 + t) * 8);
            __syncthreads();
            bf16x8 a[2], bb[5];
#pragma unroll
            for (int m = 0; m < 2; ++m)
                a[m] = *(const bf16x8*)(As + (wv * 32 + m * 16 + l15) * 32 + hi8);
#pragma unroll
            for (int n = 0; n < 5; ++n)
                bb[n] = *(const bf16x8*)(Ws + (n * 16 + l15) * 32 + hi8);
#pragma unroll
            for (int m = 0; m < 2; ++m)
#pragma unroll
                for (int n = 0; n < 5; ++n)
                    acc[m][n] = __builtin_amdgcn_mfma_f32_16x16x32_bf16(a[m], bb[n], acc[m][n], 0, 0, 0);
            __syncthreads();
        }
    }

#pragma unroll
    for (int m = 0; m < 2; ++m) {
        int ib = i0 + wv * 32 + m * 16 + (lane >> 4) * 4;
#pragma unroll
        for (int n = 0; n < 5; ++n) {
            int j = n * 16 + l15;
            if (j < 75) {
#pragma unroll
                for (int q = 0; q < 4; ++q) {
                    int i = ib + q;
                    if (i < nloc) {
                        size_t g = (size_t)(row_base + i);
                        int nn = i % N_;
                        float v = acc[m][n][q];
                        if (j < 2) {
                            props[g * PW_ + j] = v + bf2f(clsb[j]);
                            props[g * PW_ + 2 + j] = bf2f(anch[(size_t)nn * PW_ + 2 + j]);
                        } else {
                            int tt = j - 2;
                            props[g * PW_ + 4 + tt] = v + bf2f(regb[tt]) + bf2f(anch[(size_t)nn * PW_ + 4 + tt]);
                        }
                    }
                }
            }
        }
    }
}

extern "C" void kernel_launch(void* const* d_in, const int* in_sizes, int n_in,
                              void* d_out, int out_size, void* d_ws, size_t ws_size,
                              hipStream_t stream) {
    (void)in_sizes; (void)n_in; (void)out_size;

    float* props = (float*)d_out;
    float* Mbuf  = props + (size_t)ROWS_ * PW_;

    char* ws = (char*)d_ws;
    int* flags = (int*)(ws + OFF_FLAGS);
    float* feat = (float*)(ws + OFF_FEAT);
    char* canon = ws + OFF_CANON;
    unsigned short* cx    = (unsigned short*)(canon + C_X);
    unsigned short* cattw = (unsigned short*)(canon + C_ATTW);
    unsigned short* ccw   = (unsigned short*)(canon + C_CW);
    unsigned short* canch = (unsigned short*)(canon + C_ANCH);
    unsigned short* cclsw = (unsigned short*)(canon + C_CLSW);
    unsigned short* cregw = (unsigned short*)(canon + C_REGW);
    unsigned short* ccb   = (unsigned short*)(canon + C_CB);
    unsigned short* cattb = (unsigned short*)(canon + C_ATTB);
    unsigned short* cclsb = (unsigned short*)(canon + C_CLSB);
    unsigned short* cregb = (unsigned short*)(canon + C_REGB);
    int* ccut = (int*)(canon + C_CUT);
    int* cmsk = (int*)(canon + C_MASK);

    // per-batch ws need: AF/AFT/ATF (3 * N*D*2) + Mbf (N*N*2)
    const size_t base = (size_t)(12u << 20);
    const size_t sAF  = (size_t)N_ * D_ * 2;           // 3,919,872
    const size_t sMB  = (size_t)N_ * N_ * 2;           // 15,501,312
    const size_t per  = 3 * sAF + sMB;                 // ~27.3 MB
    int CN = 1;
    for (int c = 16; c >= 1; c >>= 1)
        if (ws_size >= base + (size_t)c * per) { CN = c; break; }
    unsigned short* AF  = (unsigned short*)(ws + base);
    unsigned short* AFT = AF  + (size_t)CN * N_ * D_;
    unsigned short* ATF = AFT + (size_t)CN * N_ * D_;
    unsigned short* Mbf = ATF + (size_t)CN * N_ * D_;

    k_detect<<<dim3(1), dim3(256), 0, stream>>>((const unsigned int*)d_in[3],
                                                (const unsigned int*)d_in[10],
                                                (const unsigned int*)d_in[11], flags);
    k_canon_f<<<dim3(1024), dim3(256), 0, stream>>>(d_in[0], d_in[1], d_in[2], d_in[3], d_in[4],
                                                    d_in[5], d_in[6], d_in[7], d_in[8], d_in[9],
                                                    canon, flags);
    k_canon_i<<<dim3(120), dim3(256), 0, stream>>>(d_in[10], d_in[11], canon, flags);
    k_conv<<<dim3(880), dim3(256), 0, stream>>>(cx, ccw, ccb, feat);

    const int nchunk = 16 / CN;
    for (int c = 0; c < nchunk; ++c) {
        const int bb = c * CN;
        const int rb = bb * N_;
        const int nl = CN * N_;
        const int it128 = (nl + 127) / 128;
        k_gather_af<<<dim3(N_, CN), dim3(256), 0, stream>>>(feat, ccut, cmsk, AF, bb);
        k_gather_aft<<<dim3(D_, CN), dim3(256), 0, stream>>>(feat, ccut, cmsk, AFT, bb);
        k_scores<<<dim3(22, it128), dim3(256), 0, stream>>>(AF, cattw, cattb, Mbuf, rb, nl);
        k_softmax<<<dim3(nl), dim3(256), 0, stream>>>(Mbuf, Mbf, rb);
        k_attgemm<<<dim3(6, 22, CN), dim3(256), 0, stream>>>(Mbf, AFT, ATF);
        k_head<<<dim3(it128), dim3(256), 0, stream>>>(ATF, AF, cclsw, cclsb, cregw, cregb,
                                                      canch, props, rb, nl);
    }
}

// Round 7
// 1210.405 us; speedup vs baseline: 18.3050x; 1.0013x over previous
//
#include <hip/hip_runtime.h>

#define B_    16
#define CIN_  512
#define CF_   64
#define FH_   11
#define FW_   20
#define N_    2784
#define NM1_  2783
#define D_    704
#define D2_   1408
#define ROWS_ 44544
#define PW_   77

// ---- input element counts
#define NX_     1802240
#define NCW_    32768
#define NCB_    64
#define NATTW_  1959232
#define NATTB_  2783
#define NCLSW_  2816
#define NCLSB_  2
#define NREGW_  102784
#define NREGB_  73
#define NANCH_  214368
#define NCUT_   30624

// ---- canonical ws layout (byte offsets)
#define OFF_FLAGS   0u
#define OFF_FEAT    256u
#define OFF_CANON   (1u<<20)
#define C_X      0u
#define C_ATTW   3604480u
#define C_CW     7522944u
#define C_ANCH   7588480u
#define C_CLSW   8017216u
#define C_REGW   8022848u
#define C_CB     8228416u
#define C_ATTB   8228544u
#define C_CLSB   8234112u
#define C_REGB   8234128u
#define C_CUT    8234288u
#define C_MASK   8356784u

typedef __bf16 bf16x8 __attribute__((ext_vector_type(8)));
typedef float  f32x4  __attribute__((ext_vector_type(4)));

typedef __attribute__((address_space(1))) void g_void;
typedef __attribute__((address_space(3))) void l_void;
#define GLD16(gp, lp) __builtin_amdgcn_global_load_lds((g_void*)(gp), (l_void*)(lp), 16, 0, 0)

__device__ __forceinline__ float bf2f(unsigned short u) {
    union { unsigned int u; float f; } v; v.u = ((unsigned int)u) << 16; return v.f;
}
__device__ __forceinline__ unsigned short f2bf(float f) {
    union { float f; unsigned int u; } v; v.f = f;
    unsigned int x = v.u;
    return (unsigned short)((x + 0x7FFFu + ((x >> 16) & 1u)) >> 16);
}

// ---------------- K0: dtype detection (deterministic, input-only)
__global__ __launch_bounds__(256) void k_detect(const unsigned int* __restrict__ attw,
                                                const unsigned int* __restrict__ cut,
                                                const unsigned int* __restrict__ msk,
                                                int* __restrict__ flags) {
    __shared__ int cnt[3];
    int t = threadIdx.x;
    if (t < 3) cnt[t] = 0;
    __syncthreads();
    int c0 = 0, c1 = 0, c2 = 0;
    for (int i = t; i < 2048; i += 256) {
        unsigned int e = (attw[i] >> 7) & 0xFFu;
        if (e >= 127u) c0++;
    }
    for (int i = t; i < 4096; i += 256) if (cut[i] >= 32u) c1++;
    for (int i = t; i < 4096; i += 256) if (msk[i] >= 2u)  c2++;
    atomicAdd(&cnt[0], c0); atomicAdd(&cnt[1], c1); atomicAdd(&cnt[2], c2);
    __syncthreads();
    if (t == 0) {
        flags[0] = cnt[0] > 64;
        flags[1] = cnt[1] > 64;
        flags[2] = cnt[2] > 64;
        flags[3] = 0;
    }
}

// ---------------- K0b: canonicalize all float inputs to bf16
__device__ __forceinline__ void cvt_arr(const void* s, unsigned short* d, int n, int isf32,
                                        int tid, int stride) {
    if (isf32) {
        const float* p = (const float*)s;
        for (int i = tid; i < n; i += stride) d[i] = f2bf(p[i]);
    } else {
        const unsigned short* p = (const unsigned short*)s;
        for (int i = tid; i < n; i += stride) d[i] = p[i];
    }
}

__global__ __launch_bounds__(256) void k_canon_f(const void* sx, const void* scw, const void* scb,
                                                 const void* sattw, const void* sattb,
                                                 const void* sclsw, const void* sclsb,
                                                 const void* sregw, const void* sregb,
                                                 const void* sanch, char* canon,
                                                 const int* __restrict__ flags) {
    const int isf32 = flags[0];
    const int tid = blockIdx.x * 256 + threadIdx.x;
    const int stride = gridDim.x * 256;
    cvt_arr(sx,    (unsigned short*)(canon + C_X),    NX_,    isf32, tid, stride);
    cvt_arr(sattw, (unsigned short*)(canon + C_ATTW), NATTW_, isf32, tid, stride);
    cvt_arr(scw,   (unsigned short*)(canon + C_CW),   NCW_,   isf32, tid, stride);
    cvt_arr(sanch, (unsigned short*)(canon + C_ANCH), NANCH_, isf32, tid, stride);
    cvt_arr(sclsw, (unsigned short*)(canon + C_CLSW), NCLSW_, isf32, tid, stride);
    cvt_arr(sregw, (unsigned short*)(canon + C_REGW), NREGW_, isf32, tid, stride);
    cvt_arr(scb,   (unsigned short*)(canon + C_CB),   NCB_,   isf32, tid, stride);
    cvt_arr(sattb, (unsigned short*)(canon + C_ATTB), NATTB_, isf32, tid, stride);
    cvt_arr(sclsb, (unsigned short*)(canon + C_CLSB), NCLSB_, isf32, tid, stride);
    cvt_arr(sregb, (unsigned short*)(canon + C_REGB), NREGB_, isf32, tid, stride);
}

// ---------------- K0c: canonicalize int inputs to int32
__global__ __launch_bounds__(256) void k_canon_i(const void* scut, const void* smsk,
                                                 char* canon, const int* __restrict__ flags) {
    const int cutb = flags[1], mskb = flags[2];
    int* ccut = (int*)(canon + C_CUT);
    int* cmsk = (int*)(canon + C_MASK);
    const int tid = blockIdx.x * 256 + threadIdx.x;
    const int stride = gridDim.x * 256;
    for (int i = tid; i < NCUT_; i += stride) {
        ccut[i] = cutb ? (int)((const unsigned char*)scut)[i] : ((const int*)scut)[i];
        int m = mskb ? (int)((const unsigned char*)smsk)[i] : ((const int*)smsk)[i];
        cmsk[i] = (m != 0);
    }
}

// ---------------- K1: 1x1 conv
__global__ __launch_bounds__(256) void k_conv(const unsigned short* __restrict__ x,
                                              const unsigned short* __restrict__ cw,
                                              const unsigned short* __restrict__ cb,
                                              float* __restrict__ feat) {
    int idx = blockIdx.x * 256 + threadIdx.x;           // 880*256 = 225280 exact
    int w = idx % FW_;
    int h = (idx / FW_) % FH_;
    int o = (idx / (FW_ * FH_)) % CF_;
    int b = idx / (FW_ * FH_ * CF_);
    const unsigned short* xp = x + ((size_t)(b * CIN_) * FH_ + h) * FW_ + w;
    const unsigned short* wp = cw + (size_t)o * CIN_;
    float acc = bf2f(cb[o]);
#pragma unroll 8
    for (int c = 0; c < CIN_; ++c)
        acc += bf2f(xp[(size_t)c * (FH_ * FW_)]) * bf2f(wp[c]);
    feat[idx] = acc;
}

// ---------------- K2a: AF chunk
__global__ __launch_bounds__(256) void k_gather_af(const float* __restrict__ feat,
                                                   const int* __restrict__ cut,
                                                   const int* __restrict__ inv,
                                                   unsigned short* __restrict__ AF,
                                                   int batch_base) {
    int n = blockIdx.x, bl = blockIdx.y;
    int b = batch_base + bl;
    __shared__ int cu[FH_];
    __shared__ int iv[FH_];
    int t = threadIdx.x;
    if (t < FH_) { cu[t] = cut[n * FH_ + t]; iv[t] = inv[n * FH_ + t]; }
    __syncthreads();
    unsigned short* out = AF + ((size_t)(bl * N_ + n)) * D_;
    for (int d = t; d < D_; d += 256) {
        int c = d / FH_, h = d - c * FH_;
        float v = iv[h] ? 0.f : feat[((b * CF_ + c) * FH_ + h) * FW_ + cu[h]];
        out[d] = f2bf(v);
    }
}

// ---------------- K2b: AFT chunk
__global__ __launch_bounds__(256) void k_gather_aft(const float* __restrict__ feat,
                                                    const int* __restrict__ cut,
                                                    const int* __restrict__ inv,
                                                    unsigned short* __restrict__ AFT,
                                                    int batch_base) {
    int d = blockIdx.x, bl = blockIdx.y;
    int b = batch_base + bl;
    int c = d / FH_, h = d - c * FH_;
    const float* fp = feat + ((b * CF_ + c) * FH_ + h) * FW_;
    unsigned short* out = AFT + ((size_t)(bl * D_ + d)) * N_;
    for (int n = threadIdx.x; n < N_; n += 256) {
        int w = cut[n * FH_ + h];
        float v = inv[n * FH_ + h] ? 0.f : fp[w];
        out[n] = f2bf(v);
    }
}

// ---------------- K3a: MFMA scores GEMM (double-buffered, counted vmcnt), scatter into M (f32)
__global__ __launch_bounds__(256) void k_scores(const unsigned short* __restrict__ AF,
                                                const unsigned short* __restrict__ attw,
                                                const unsigned short* __restrict__ attb,
                                                float* __restrict__ Mbuf,
                                                int row_base, int nloc) {
    __shared__ __bf16 As[2][128 * 32];
    __shared__ __bf16 Bs[2][128 * 32];
    const int t = threadIdx.x;
    const int jt = blockIdx.x, it = blockIdx.y;
    const int i0 = it * 128, j0 = jt * 128;
    const int lane = t & 63, wv = t >> 6;
    const int wr = wv >> 1, wc = wv & 1;
    const int l15 = lane & 15, hi8 = (lane >> 4) * 8;

    f32x4 zero = {0.f, 0.f, 0.f, 0.f};
    f32x4 acc[4][4];
#pragma unroll
    for (int m = 0; m < 4; ++m)
#pragma unroll
        for (int n = 0; n < 4; ++n) acc[m][n] = zero;

    const int s0 = t, s1 = t + 256;
    const int ar0 = s0 >> 2, ac0 = (s0 & 3) * 8;
    const int ar1 = s1 >> 2, ac1 = (s1 & 3) * 8;
    int ir0 = i0 + ar0; if (ir0 > nloc - 1) ir0 = nloc - 1;
    int ir1 = i0 + ar1; if (ir1 > nloc - 1) ir1 = nloc - 1;
    int jr0 = j0 + ar0; if (jr0 > NM1_ - 1) jr0 = NM1_ - 1;
    int jr1 = j0 + ar1; if (jr1 > NM1_ - 1) jr1 = NM1_ - 1;
    const unsigned short* a0 = AF + (size_t)ir0 * D_ + ac0;
    const unsigned short* a1 = AF + (size_t)ir1 * D_ + ac1;
    const unsigned short* b0 = attw + (size_t)jr0 * D_ + ac0;
    const unsigned short* b1 = attw + (size_t)jr1 * D_ + ac1;

    const int NT = D_ / 32;   // 22
    // prologue: stage tile 0 into buf 0
    GLD16(a0 + 0, As[0] + s0 * 8);
    GLD16(a1 + 0, As[0] + s1 * 8);
    GLD16(b0 + 0, Bs[0] + s0 * 8);
    GLD16(b1 + 0, Bs[0] + s1 * 8);

    for (int kt = 0; kt < NT; ++kt) {
        const int cur = kt & 1;
        if (kt + 1 < NT) {
            const int nk = (kt + 1) * 32;
            GLD16(a0 + nk, As[cur ^ 1] + s0 * 8);
            GLD16(a1 + nk, As[cur ^ 1] + s1 * 8);
            GLD16(b0 + nk, Bs[cur ^ 1] + s0 * 8);
            GLD16(b1 + nk, Bs[cur ^ 1] + s1 * 8);
            asm volatile("s_waitcnt vmcnt(4)" ::: "memory");
        } else {
            asm volatile("s_waitcnt vmcnt(0)" ::: "memory");
        }
        __builtin_amdgcn_sched_barrier(0);
        __builtin_amdgcn_s_barrier();
        bf16x8 a[4], bb[4];
#pragma unroll
        for (int m = 0; m < 4; ++m)
            a[m] = *(const bf16x8*)(As[cur] + (wr * 64 + m * 16 + l15) * 32 + hi8);
#pragma unroll
        for (int n = 0; n < 4; ++n)
            bb[n] = *(const bf16x8*)(Bs[cur] + (wc * 64 + n * 16 + l15) * 32 + hi8);
#pragma unroll
        for (int m = 0; m < 4; ++m)
#pragma unroll
            for (int n = 0; n < 4; ++n)
                acc[m][n] = __builtin_amdgcn_mfma_f32_16x16x32_bf16(a[m], bb[n], acc[m][n], 0, 0, 0);
        __builtin_amdgcn_s_barrier();
        __builtin_amdgcn_sched_barrier(0);
    }

#pragma unroll
    for (int m = 0; m < 4; ++m) {
        int ib = i0 + wr * 64 + m * 16 + (lane >> 4) * 4;
#pragma unroll
        for (int n = 0; n < 4; ++n) {
            int j = j0 + wc * 64 + n * 16 + l15;
            if (j < NM1_) {
                float bias = bf2f(attb[j]);
#pragma unroll
                for (int q = 0; q < 4; ++q) {
                    int ii = ib + q;
                    if (ii < nloc) {
                        int r = ii % N_;
                        int c = j + (j >= r);
                        Mbuf[(size_t)(row_base + ii) * N_ + c] = acc[m][n][q] + bias;
                    }
                }
            }
        }
    }
}

// ---------------- K3b: f32 row softmax, dual-write f32 M (d_out) + bf16 shadow (ws)
__global__ __launch_bounds__(256) void k_softmax(float* __restrict__ Mbuf,
                                                 unsigned short* __restrict__ Mbf,
                                                 int row_base) {
    const int il = blockIdx.x;
    const int i = row_base + il;
    const int r = i % N_;
    float4* row = (float4*)(Mbuf + (size_t)i * N_);
    unsigned short* orow = Mbf + (size_t)il * N_;
    const int t = threadIdx.x;
    float4 f[3];
#pragma unroll
    for (int q = 0; q < 3; ++q) {
        int c4 = t + 256 * q;
        if (c4 < N_ / 4) f[q] = row[c4];
        else { f[q].x = -1e30f; f[q].y = -1e30f; f[q].z = -1e30f; f[q].w = -1e30f; }
        int b = c4 * 4;
        if (b + 0 == r) f[q].x = -1e30f;
        if (b + 1 == r) f[q].y = -1e30f;
        if (b + 2 == r) f[q].z = -1e30f;
        if (b + 3 == r) f[q].w = -1e30f;
    }
    float m = -1e30f;
#pragma unroll
    for (int q = 0; q < 3; ++q)
        m = fmaxf(m, fmaxf(fmaxf(f[q].x, f[q].y), fmaxf(f[q].z, f[q].w)));
#pragma unroll
    for (int off = 32; off >= 1; off >>= 1) m = fmaxf(m, __shfl_xor(m, off, 64));
    __shared__ float red[4];
    if ((t & 63) == 0) red[t >> 6] = m;
    __syncthreads();
    m = fmaxf(fmaxf(red[0], red[1]), fmaxf(red[2], red[3]));

    float s = 0.f;
#pragma unroll
    for (int q = 0; q < 3; ++q) {
        f[q].x = __expf(f[q].x - m); f[q].y = __expf(f[q].y - m);
        f[q].z = __expf(f[q].z - m); f[q].w = __expf(f[q].w - m);
        s += f[q].x + f[q].y + f[q].z + f[q].w;
    }
#pragma unroll
    for (int off = 32; off >= 1; off >>= 1) s += __shfl_xor(s, off, 64);
    __shared__ float red2[4];
    if ((t & 63) == 0) red2[t >> 6] = s;
    __syncthreads();
    s = red2[0] + red2[1] + red2[2] + red2[3];
    float inv = 1.0f / s;
#pragma unroll
    for (int q = 0; q < 3; ++q) {
        int c4 = t + 256 * q;
        if (c4 < N_ / 4) {
            float4 o; o.x = f[q].x * inv; o.y = f[q].y * inv;
            o.z = f[q].z * inv; o.w = f[q].w * inv;
            row[c4] = o;
            union { unsigned short u[4]; uint2 v; } p;
            p.u[0] = f2bf(o.x); p.u[1] = f2bf(o.y);
            p.u[2] = f2bf(o.z); p.u[3] = f2bf(o.w);
            *(uint2*)(orow + c4 * 4) = p.v;
        }
    }
}

// ---------------- K4: MFMA att_feat = Mbf(bf16) @ AF (double-buffered, counted vmcnt)
__global__ __launch_bounds__(256) void k_attgemm(const unsigned short* __restrict__ Mbf,
                                                 const unsigned short* __restrict__ AFT,
                                                 unsigned short* __restrict__ ATF) {
    __shared__ __bf16 As[2][128 * 32];
    __shared__ __bf16 Bs[2][128 * 32];
    const int t = threadIdx.x;
    const int jt = blockIdx.x, it = blockIdx.y, bl = blockIdx.z;
    const int i0 = it * 128, j0 = jt * 128;
    const int lane = t & 63, wv = t >> 6;
    const int wr = wv >> 1, wc = wv & 1;
    const int l15 = lane & 15, hi8 = (lane >> 4) * 8;

    f32x4 zero = {0.f, 0.f, 0.f, 0.f};
    f32x4 acc[4][4];
#pragma unroll
    for (int m = 0; m < 4; ++m)
#pragma unroll
        for (int n = 0; n < 4; ++n) acc[m][n] = zero;

    const int s0 = t, s1 = t + 256;
    int ir0 = i0 + (s0 >> 2); if (ir0 > N_ - 1) ir0 = N_ - 1;
    int ir1 = i0 + (s1 >> 2); if (ir1 > N_ - 1) ir1 = N_ - 1;
    int jr0 = j0 + (s0 >> 2); if (jr0 > D_ - 1) jr0 = D_ - 1;
    int jr1 = j0 + (s1 >> 2); if (jr1 > D_ - 1) jr1 = D_ - 1;
    const int ac0 = (s0 & 3) * 8, ac1 = (s1 & 3) * 8;
    const unsigned short* a0 = Mbf + ((size_t)bl * N_ + ir0) * N_ + ac0;
    const unsigned short* a1 = Mbf + ((size_t)bl * N_ + ir1) * N_ + ac1;
    const unsigned short* b0 = AFT + (size_t)(bl * D_ + jr0) * N_ + ac0;
    const unsigned short* b1 = AFT + (size_t)(bl * D_ + jr1) * N_ + ac1;

    const int NT = N_ / 32;   // 87
    GLD16(a0 + 0, As[0] + s0 * 8);
    GLD16(a1 + 0, As[0] + s1 * 8);
    GLD16(b0 + 0, Bs[0] + s0 * 8);
    GLD16(b1 + 0, Bs[0] + s1 * 8);

    for (int kt = 0; kt < NT; ++kt) {
        const int cur = kt & 1;
        if (kt + 1 < NT) {
            const int nk = (kt + 1) * 32;
            GLD16(a0 + nk, As[cur ^ 1] + s0 * 8);
            GLD16(a1 + nk, As[cur ^ 1] + s1 * 8);
            GLD16(b0 + nk, Bs[cur ^ 1] + s0 * 8);
            GLD16(b1 + nk, Bs[cur ^ 1] + s1 * 8);
            asm volatile("s_waitcnt vmcnt(4)" ::: "memory");
        } else {
            asm volatile("s_waitcnt vmcnt(0)" ::: "memory");
        }
        __builtin_amdgcn_sched_barrier(0);
        __builtin_amdgcn_s_barrier();
        bf16x8 a[4], bb[4];
#pragma unroll
        for (int m = 0; m < 4; ++m)
            a[m] = *(const bf16x8*)(As[cur] + (wr * 64 + m * 16 + l15) * 32 + hi8);
#pragma unroll
        for (int n = 0; n < 4; ++n)
            bb[n] = *(const bf16x8*)(Bs[cur] + (wc * 64 + n * 16 + l15) * 32 + hi8);
#pragma unroll
        for (int m = 0; m < 4; ++m)
#pragma unroll
            for (int n = 0; n < 4; ++n)
                acc[m][n] = __builtin_amdgcn_mfma_f32_16x16x32_bf16(a[m], bb[n], acc[m][n], 0, 0, 0);
        __builtin_amdgcn_s_barrier();
        __builtin_amdgcn_sched_barrier(0);
    }

#pragma unroll
    for (int m = 0; m < 4; ++m) {
        int rb = i0 + wr * 64 + m * 16 + (lane >> 4) * 4;
#pragma unroll
        for (int n = 0; n < 4; ++n) {
            int d = j0 + wc * 64 + n * 16 + l15;
            if (d < D_) {
#pragma unroll
                for (int q = 0; q < 4; ++q) {
                    int rr = rb + q;
                    if (rr < N_)
                        ATF[((size_t)(bl * N_ + rr)) * D_ + d] = f2bf(acc[m][n][q]);
                }
            }
        }
    }
}

// ---------------- K5: MFMA heads + fused props epilogue (f32 out)
__global__ __launch_bounds__(256) void k_head(const unsigned short* __restrict__ ATF,
                                              const unsigned short* __restrict__ AF,
                                              const unsigned short* __restrict__ clsw,
                                              const unsigned short* __restrict__ clsb,
                                              const unsigned short* __restrict__ regw,
                                              const unsigned short* __restrict__ regb,
                                              const unsigned short* __restrict__ anch,
                                              float* __restrict__ props,
                                              int row_base, int nloc) {
    __shared__ __bf16 As[128 * 32];
    __shared__ __bf16 Ws[80 * 32];
    const int t = threadIdx.x;
    const int i0 = blockIdx.x * 128;
    const int lane = t & 63, wv = t >> 6;
    const int l15 = lane & 15, hi8 = (lane >> 4) * 8;

    f32x4 zero = {0.f, 0.f, 0.f, 0.f};
    f32x4 acc[2][5];
#pragma unroll
    for (int m = 0; m < 2; ++m)
#pragma unroll
        for (int n = 0; n < 5; ++n) acc[m][n] = zero;

    const int s0 = t, s1 = t + 256;
    const int ar0 = s0 >> 2, ac0 = (s0 & 3) * 8;
    const int ar1 = s1 >> 2, ac1 = (s1 & 3) * 8;
    int ir0 = i0 + ar0; if (ir0 > nloc - 1) ir0 = nloc - 1;
    int ir1 = i0 + ar1; if (ir1 > nloc - 1) ir1 = nloc - 1;
    const unsigned short* w0base = (ar0 < 2) ? (clsw + (size_t)ar0 * D2_)
                                             : (regw + (size_t)(ar0 - 2) * D2_);
    int r1 = 64 + (t >> 2);
    int rc = r1 < 75 ? r1 : 74;
    const unsigned short* w1base = regw + (size_t)(rc - 2) * D2_;
    const int w1c = (t & 3) * 8;

    for (int p = 0; p < 2; ++p) {
        const unsigned short* Asrc = (p == 0) ? ATF : AF;
        const int wcol = p * D_;
        for (int k0 = 0; k0 < D_; k0 += 32) {
            GLD16(Asrc + (size_t)ir0 * D_ + ac0 + k0, As + s0 * 8);
            GLD16(Asrc + (size_t)ir1 * D_ + ac1 + k0, As + s1 * 8);
            GLD16(w0base + wcol + k0 + ac0, Ws + s0 * 8);
            if (t < 64) GLD16(w1base + wcol + k0 + w1c, Ws + (size_t)(256 + t) * 8);
            __syncthreads();
            bf16x8 a[2], bb[5];
#pragma unroll
            for (int m = 0; m < 2; ++m)
                a[m] = *(const bf16x8*)(As + (wv * 32 + m * 16 + l15) * 32 + hi8);
#pragma unroll
            for (int n = 0; n < 5; ++n)
                bb[n] = *(const bf16x8*)(Ws + (n * 16 + l15) * 32 + hi8);
#pragma unroll
            for (int m = 0; m < 2; ++m)
#pragma unroll
                for (int n = 0; n < 5; ++n)
                    acc[m][n] = __builtin_amdgcn_mfma_f32_16x16x32_bf16(a[m], bb[n], acc[m][n], 0, 0, 0);
            __syncthreads();
        }
    }

#pragma unroll
    for (int m = 0; m < 2; ++m) {
        int ib = i0 + wv * 32 + m * 16 + (lane >> 4) * 4;
#pragma unroll
        for (int n = 0; n < 5; ++n) {
            int j = n * 16 + l15;
            if (j < 75) {
#pragma unroll
                for (int q = 0; q < 4; ++q) {
                    int i = ib + q;
                    if (i < nloc) {
                        size_t g = (size_t)(row_base + i);
                        int nn = i % N_;
                        float v = acc[m][n][q];
                        if (j < 2) {
                            props[g * PW_ + j] = v + bf2f(clsb[j]);
                            props[g * PW_ + 2 + j] = bf2f(anch[(size_t)nn * PW_ + 2 + j]);
                        } else {
                            int tt = j - 2;
                            props[g * PW_ + 4 + tt] = v + bf2f(regb[tt]) + bf2f(anch[(size_t)nn * PW_ + 4 + tt]);
                        }
                    }
                }
            }
        }
    }
}

extern "C" void kernel_launch(void* const* d_in, const int* in_sizes, int n_in,
                              void* d_out, int out_size, void* d_ws, size_t ws_size,
                              hipStream_t stream) {
    (void)in_sizes; (void)n_in; (void)out_size;

    float* props = (float*)d_out;
    float* Mbuf  = props + (size_t)ROWS_ * PW_;

    char* ws = (char*)d_ws;
    int* flags = (int*)(ws + OFF_FLAGS);
    float* feat = (float*)(ws + OFF_FEAT);
    char* canon = ws + OFF_CANON;
    unsigned short* cx    = (unsigned short*)(canon + C_X);
    unsigned short* cattw = (unsigned short*)(canon + C_ATTW);
    unsigned short* ccw   = (unsigned short*)(canon + C_CW);
    unsigned short* canch = (unsigned short*)(canon + C_ANCH);
    unsigned short* cclsw = (unsigned short*)(canon + C_CLSW);
    unsigned short* cregw = (unsigned short*)(canon + C_REGW);
    unsigned short* ccb   = (unsigned short*)(canon + C_CB);
    unsigned short* cattb = (unsigned short*)(canon + C_ATTB);
    unsigned short* cclsb = (unsigned short*)(canon + C_CLSB);
    unsigned short* cregb = (unsigned short*)(canon + C_REGB);
    int* ccut = (int*)(canon + C_CUT);
    int* cmsk = (int*)(canon + C_MASK);

    // per-batch ws need: AF/AFT/ATF (3 * N*D*2) + Mbf (N*N*2)
    const size_t base = (size_t)(12u << 20);
    const size_t sAF  = (size_t)N_ * D_ * 2;           // 3,919,872
    const size_t sMB  = (size_t)N_ * N_ * 2;           // 15,501,312
    const size_t per  = 3 * sAF + sMB;                 // ~27.3 MB
    int CN = 1;
    for (int c = 16; c >= 1; c >>= 1)
        if (ws_size >= base + (size_t)c * per) { CN = c; break; }
    unsigned short* AF  = (unsigned short*)(ws + base);
    unsigned short* AFT = AF  + (size_t)CN * N_ * D_;
    unsigned short* ATF = AFT + (size_t)CN * N_ * D_;
    unsigned short* Mbf = ATF + (size_t)CN * N_ * D_;

    k_detect<<<dim3(1), dim3(256), 0, stream>>>((const unsigned int*)d_in[3],
                                                (const unsigned int*)d_in[10],
                                                (const unsigned int*)d_in[11], flags);
    k_canon_f<<<dim3(1024), dim3(256), 0, stream>>>(d_in[0], d_in[1], d_in[2], d_in[3], d_in[4],
                                                    d_in[5], d_in[6], d_in[7], d_in[8], d_in[9],
                                                    canon, flags);
    k_canon_i<<<dim3(120), dim3(256), 0, stream>>>(d_in[10], d_in[11], canon, flags);
    k_conv<<<dim3(880), dim3(256), 0, stream>>>(cx, ccw, ccb, feat);

    const int nchunk = 16 / CN;
    for (int c = 0; c < nchunk; ++c) {
        const int bb = c * CN;
        const int rb = bb * N_;
        const int nl = CN * N_;
        const int it128 = (nl + 127) / 128;
        k_gather_af<<<dim3(N_, CN), dim3(256), 0, stream>>>(feat, ccut, cmsk, AF, bb);
        k_gather_aft<<<dim3(D_, CN), dim3(256), 0, stream>>>(feat, ccut, cmsk, AFT, bb);
        k_scores<<<dim3(22, it128), dim3(256), 0, stream>>>(AF, cattw, cattb, Mbuf, rb, nl);
        k_softmax<<<dim3(nl), dim3(256), 0, stream>>>(Mbuf, Mbf, rb);
        k_attgemm<<<dim3(6, 22, CN), dim3(256), 0, stream>>>(Mbf, AFT, ATF);
        k_head<<<dim3(it128), dim3(256), 0, stream>>>(ATF, AF, cclsw, cclsb, cregw, cregb,
                                                      canch, props, rb, nl);
    }
}

// Round 8
// 1080.214 us; speedup vs baseline: 20.5111x; 1.1205x over previous
//
#include <hip/hip_runtime.h>

#define B_    16
#define CIN_  512
#define CF_   64
#define FH_   11
#define FW_   20
#define N_    2784
#define NM1_  2783
#define D_    704
#define D2_   1408
#define ROWS_ 44544
#define PW_   77

// ---- input element counts
#define NX_     1802240
#define NCW_    32768
#define NCB_    64
#define NATTW_  1959232
#define NATTB_  2783
#define NCLSW_  2816
#define NCLSB_  2
#define NREGW_  102784
#define NREGB_  73
#define NANCH_  214368
#define NCUT_   30624

// ---- canonical ws layout (byte offsets)
#define OFF_FLAGS   0u
#define OFF_FEAT    256u
#define OFF_CANON   (1u<<20)
#define C_X      0u
#define C_ATTW   3604480u
#define C_CW     7522944u
#define C_ANCH   7588480u
#define C_CLSW   8017216u
#define C_REGW   8022848u
#define C_CB     8228416u
#define C_ATTB   8228544u
#define C_CLSB   8234112u
#define C_REGB   8234128u
#define C_CUT    8234288u
#define C_MASK   8356784u

typedef __bf16 bf16x8 __attribute__((ext_vector_type(8)));
typedef float  f32x4  __attribute__((ext_vector_type(4)));

typedef __attribute__((address_space(1))) void g_void;
typedef __attribute__((address_space(3))) void l_void;
#define GLD16(gp, lp) __builtin_amdgcn_global_load_lds((g_void*)(gp), (l_void*)(lp), 16, 0, 0)

__device__ __forceinline__ float bf2f(unsigned short u) {
    union { unsigned int u; float f; } v; v.u = ((unsigned int)u) << 16; return v.f;
}
__device__ __forceinline__ unsigned short f2bf(float f) {
    union { float f; unsigned int u; } v; v.f = f;
    unsigned int x = v.u;
    return (unsigned short)((x + 0x7FFFu + ((x >> 16) & 1u)) >> 16);
}

// ---------------- K0: dtype detection (deterministic, input-only)
__global__ __launch_bounds__(256) void k_detect(const unsigned int* __restrict__ attw,
                                                const unsigned int* __restrict__ cut,
                                                const unsigned int* __restrict__ msk,
                                                int* __restrict__ flags) {
    __shared__ int cnt[3];
    int t = threadIdx.x;
    if (t < 3) cnt[t] = 0;
    __syncthreads();
    int c0 = 0, c1 = 0, c2 = 0;
    for (int i = t; i < 2048; i += 256) {
        unsigned int e = (attw[i] >> 7) & 0xFFu;
        if (e >= 127u) c0++;
    }
    for (int i = t; i < 4096; i += 256) if (cut[i] >= 32u) c1++;
    for (int i = t; i < 4096; i += 256) if (msk[i] >= 2u)  c2++;
    atomicAdd(&cnt[0], c0); atomicAdd(&cnt[1], c1); atomicAdd(&cnt[2], c2);
    __syncthreads();
    if (t == 0) {
        flags[0] = cnt[0] > 64;
        flags[1] = cnt[1] > 64;
        flags[2] = cnt[2] > 64;
        flags[3] = 0;
    }
}

// ---------------- K0b: canonicalize all float inputs to bf16
__device__ __forceinline__ void cvt_arr(const void* s, unsigned short* d, int n, int isf32,
                                        int tid, int stride) {
    if (isf32) {
        const float* p = (const float*)s;
        for (int i = tid; i < n; i += stride) d[i] = f2bf(p[i]);
    } else {
        const unsigned short* p = (const unsigned short*)s;
        for (int i = tid; i < n; i += stride) d[i] = p[i];
    }
}

__global__ __launch_bounds__(256) void k_canon_f(const void* sx, const void* scw, const void* scb,
                                                 const void* sattw, const void* sattb,
                                                 const void* sclsw, const void* sclsb,
                                                 const void* sregw, const void* sregb,
                                                 const void* sanch, char* canon,
                                                 const int* __restrict__ flags) {
    const int isf32 = flags[0];
    const int tid = blockIdx.x * 256 + threadIdx.x;
    const int stride = gridDim.x * 256;
    cvt_arr(sx,    (unsigned short*)(canon + C_X),    NX_,    isf32, tid, stride);
    cvt_arr(sattw, (unsigned short*)(canon + C_ATTW), NATTW_, isf32, tid, stride);
    cvt_arr(scw,   (unsigned short*)(canon + C_CW),   NCW_,   isf32, tid, stride);
    cvt_arr(sanch, (unsigned short*)(canon + C_ANCH), NANCH_, isf32, tid, stride);
    cvt_arr(sclsw, (unsigned short*)(canon + C_CLSW), NCLSW_, isf32, tid, stride);
    cvt_arr(sregw, (unsigned short*)(canon + C_REGW), NREGW_, isf32, tid, stride);
    cvt_arr(scb,   (unsigned short*)(canon + C_CB),   NCB_,   isf32, tid, stride);
    cvt_arr(sattb, (unsigned short*)(canon + C_ATTB), NATTB_, isf32, tid, stride);
    cvt_arr(sclsb, (unsigned short*)(canon + C_CLSB), NCLSB_, isf32, tid, stride);
    cvt_arr(sregb, (unsigned short*)(canon + C_REGB), NREGB_, isf32, tid, stride);
}

// ---------------- K0c: canonicalize int inputs to int32
__global__ __launch_bounds__(256) void k_canon_i(const void* scut, const void* smsk,
                                                 char* canon, const int* __restrict__ flags) {
    const int cutb = flags[1], mskb = flags[2];
    int* ccut = (int*)(canon + C_CUT);
    int* cmsk = (int*)(canon + C_MASK);
    const int tid = blockIdx.x * 256 + threadIdx.x;
    const int stride = gridDim.x * 256;
    for (int i = tid; i < NCUT_; i += stride) {
        ccut[i] = cutb ? (int)((const unsigned char*)scut)[i] : ((const int*)scut)[i];
        int m = mskb ? (int)((const unsigned char*)smsk)[i] : ((const int*)smsk)[i];
        cmsk[i] = (m != 0);
    }
}

// ---------------- K1: 1x1 conv
__global__ __launch_bounds__(256) void k_conv(const unsigned short* __restrict__ x,
                                              const unsigned short* __restrict__ cw,
                                              const unsigned short* __restrict__ cb,
                                              float* __restrict__ feat) {
    int idx = blockIdx.x * 256 + threadIdx.x;           // 880*256 = 225280 exact
    int w = idx % FW_;
    int h = (idx / FW_) % FH_;
    int o = (idx / (FW_ * FH_)) % CF_;
    int b = idx / (FW_ * FH_ * CF_);
    const unsigned short* xp = x + ((size_t)(b * CIN_) * FH_ + h) * FW_ + w;
    const unsigned short* wp = cw + (size_t)o * CIN_;
    float acc = bf2f(cb[o]);
#pragma unroll 8
    for (int c = 0; c < CIN_; ++c)
        acc += bf2f(xp[(size_t)c * (FH_ * FW_)]) * bf2f(wp[c]);
    feat[idx] = acc;
}

// ---------------- K2a: AF chunk
__global__ __launch_bounds__(256) void k_gather_af(const float* __restrict__ feat,
                                                   const int* __restrict__ cut,
                                                   const int* __restrict__ inv,
                                                   unsigned short* __restrict__ AF,
                                                   int batch_base) {
    int n = blockIdx.x, bl = blockIdx.y;
    int b = batch_base + bl;
    __shared__ int cu[FH_];
    __shared__ int iv[FH_];
    int t = threadIdx.x;
    if (t < FH_) { cu[t] = cut[n * FH_ + t]; iv[t] = inv[n * FH_ + t]; }
    __syncthreads();
    unsigned short* out = AF + ((size_t)(bl * N_ + n)) * D_;
    for (int d = t; d < D_; d += 256) {
        int c = d / FH_, h = d - c * FH_;
        float v = iv[h] ? 0.f : feat[((b * CF_ + c) * FH_ + h) * FW_ + cu[h]];
        out[d] = f2bf(v);
    }
}

// ---------------- K2b: AFT chunk
__global__ __launch_bounds__(256) void k_gather_aft(const float* __restrict__ feat,
                                                    const int* __restrict__ cut,
                                                    const int* __restrict__ inv,
                                                    unsigned short* __restrict__ AFT,
                                                    int batch_base) {
    int d = blockIdx.x, bl = blockIdx.y;
    int b = batch_base + bl;
    int c = d / FH_, h = d - c * FH_;
    const float* fp = feat + ((b * CF_ + c) * FH_ + h) * FW_;
    unsigned short* out = AFT + ((size_t)(bl * D_ + d)) * N_;
    for (int n = threadIdx.x; n < N_; n += 256) {
        int w = cut[n * FH_ + h];
        float v = inv[n * FH_ + h] ? 0.f : fp[w];
        out[n] = f2bf(v);
    }
}

// ---------------- K3a: MFMA scores GEMM (dbuf + swizzled LDS), raw bf16 scores -> Mbf (shifted)
__global__ __launch_bounds__(256) void k_scores(const unsigned short* __restrict__ AF,
                                                const unsigned short* __restrict__ attw,
                                                const unsigned short* __restrict__ attb,
                                                unsigned short* __restrict__ Mbf,
                                                int nloc) {
    __shared__ __bf16 As[2][128 * 32];
    __shared__ __bf16 Bs[2][128 * 32];
    const int t = threadIdx.x;
    const int jt = blockIdx.x, it = blockIdx.y;
    const int i0 = it * 128, j0 = jt * 128;
    const int lane = t & 63, wv = t >> 6;
    const int wr = wv >> 1, wc = wv & 1;
    const int l15 = lane & 15;
    // swizzled fragment slot: logical chunk (lane>>4), row-xor (l15>>1)&3
    const int hix = (((lane >> 4) ^ ((l15 >> 1) & 3)) * 8);

    f32x4 zero = {0.f, 0.f, 0.f, 0.f};
    f32x4 acc[4][4];
#pragma unroll
    for (int m = 0; m < 4; ++m)
#pragma unroll
        for (int n = 0; n < 4; ++n) acc[m][n] = zero;

    const int s0 = t, s1 = t + 256;
    const int ar0 = s0 >> 2, ar1 = s1 >> 2;
    // source-chunk permutation so linear GLD16 dest yields swizzled storage (rule #21)
    const int ac0 = (((s0 & 3) ^ ((s0 >> 3) & 3)) * 8);
    const int ac1 = (((s1 & 3) ^ ((s1 >> 3) & 3)) * 8);
    int ir0 = i0 + ar0; if (ir0 > nloc - 1) ir0 = nloc - 1;
    int ir1 = i0 + ar1; if (ir1 > nloc - 1) ir1 = nloc - 1;
    int jr0 = j0 + ar0; if (jr0 > NM1_ - 1) jr0 = NM1_ - 1;
    int jr1 = j0 + ar1; if (jr1 > NM1_ - 1) jr1 = NM1_ - 1;
    const unsigned short* a0 = AF + (size_t)ir0 * D_ + ac0;
    const unsigned short* a1 = AF + (size_t)ir1 * D_ + ac1;
    const unsigned short* b0 = attw + (size_t)jr0 * D_ + ac0;
    const unsigned short* b1 = attw + (size_t)jr1 * D_ + ac1;

    const int NT = D_ / 32;   // 22
    GLD16(a0 + 0, As[0] + s0 * 8);
    GLD16(a1 + 0, As[0] + s1 * 8);
    GLD16(b0 + 0, Bs[0] + s0 * 8);
    GLD16(b1 + 0, Bs[0] + s1 * 8);

    for (int kt = 0; kt < NT; ++kt) {
        const int cur = kt & 1;
        if (kt + 1 < NT) {
            const int nk = (kt + 1) * 32;
            GLD16(a0 + nk, As[cur ^ 1] + s0 * 8);
            GLD16(a1 + nk, As[cur ^ 1] + s1 * 8);
            GLD16(b0 + nk, Bs[cur ^ 1] + s0 * 8);
            GLD16(b1 + nk, Bs[cur ^ 1] + s1 * 8);
            asm volatile("s_waitcnt vmcnt(4)" ::: "memory");
        } else {
            asm volatile("s_waitcnt vmcnt(0)" ::: "memory");
        }
        __builtin_amdgcn_sched_barrier(0);
        __builtin_amdgcn_s_barrier();
        bf16x8 a[4], bb[4];
#pragma unroll
        for (int m = 0; m < 4; ++m)
            a[m] = *(const bf16x8*)(As[cur] + (wr * 64 + m * 16 + l15) * 32 + hix);
#pragma unroll
        for (int n = 0; n < 4; ++n)
            bb[n] = *(const bf16x8*)(Bs[cur] + (wc * 64 + n * 16 + l15) * 32 + hix);
#pragma unroll
        for (int m = 0; m < 4; ++m)
#pragma unroll
            for (int n = 0; n < 4; ++n)
                acc[m][n] = __builtin_amdgcn_mfma_f32_16x16x32_bf16(a[m], bb[n], acc[m][n], 0, 0, 0);
        __builtin_amdgcn_s_barrier();
        __builtin_amdgcn_sched_barrier(0);
    }

#pragma unroll
    for (int m = 0; m < 4; ++m) {
        int ib = i0 + wr * 64 + m * 16 + (lane >> 4) * 4;
#pragma unroll
        for (int n = 0; n < 4; ++n) {
            int j = j0 + wc * 64 + n * 16 + l15;
            if (j < NM1_) {
                float bias = bf2f(attb[j]);
#pragma unroll
                for (int q = 0; q < 4; ++q) {
                    int ii = ib + q;
                    if (ii < nloc) {
                        int r = ii % N_;
                        int c = j + (j >= r);
                        Mbf[(size_t)ii * N_ + c] = f2bf(acc[m][n][q] + bias);
                    }
                }
            }
        }
    }
}

// ---------------- K3b: bf16 row softmax IN PLACE + f32 M write to d_out (diag -> exact 0)
__global__ __launch_bounds__(256) void k_softmax(unsigned short* __restrict__ Mbf,
                                                 float* __restrict__ Mout,
                                                 int row_base) {
    const int il = blockIdx.x;
    const int r = il % N_;
    unsigned short* srow = Mbf + (size_t)il * N_;
    float* orow = Mout + (size_t)(row_base + il) * N_;
    const int t = threadIdx.x;
    float f[16];
#pragma unroll
    for (int q = 0; q < 2; ++q) {
        int c8 = t + 256 * q;
        if (c8 < N_ / 8) {
            uint4 u = *(const uint4*)(srow + c8 * 8);
            const unsigned short* pu = (const unsigned short*)&u;
#pragma unroll
            for (int e = 0; e < 8; ++e) {
                int c = c8 * 8 + e;
                float v = bf2f(pu[e]);
                f[q * 8 + e] = (c == r) ? -1e30f : v;
            }
        } else {
#pragma unroll
            for (int e = 0; e < 8; ++e) f[q * 8 + e] = -1e30f;
        }
    }
    float m = -1e30f;
#pragma unroll
    for (int q = 0; q < 16; ++q) m = fmaxf(m, f[q]);
#pragma unroll
    for (int off = 32; off >= 1; off >>= 1) m = fmaxf(m, __shfl_xor(m, off, 64));
    __shared__ float red[4];
    if ((t & 63) == 0) red[t >> 6] = m;
    __syncthreads();
    m = fmaxf(fmaxf(red[0], red[1]), fmaxf(red[2], red[3]));

    float s = 0.f;
#pragma unroll
    for (int q = 0; q < 16; ++q) { float e = __expf(f[q] - m); f[q] = e; s += e; }
#pragma unroll
    for (int off = 32; off >= 1; off >>= 1) s += __shfl_xor(s, off, 64);
    __shared__ float red2[4];
    if ((t & 63) == 0) red2[t >> 6] = s;
    __syncthreads();
    s = red2[0] + red2[1] + red2[2] + red2[3];
    float inv = 1.0f / s;
#pragma unroll
    for (int q = 0; q < 2; ++q) {
        int c8 = t + 256 * q;
        if (c8 < N_ / 8) {
            float o[8];
            union { unsigned short u[8]; uint4 v; } pb;
#pragma unroll
            for (int e = 0; e < 8; ++e) {
                o[e] = f[q * 8 + e] * inv;     // diag: exp(-1e30-m)=0 -> exact 0
                pb.u[e] = f2bf(o[e]);
            }
            float4 o0 = {o[0], o[1], o[2], o[3]};
            float4 o1 = {o[4], o[5], o[6], o[7]};
            *(float4*)(orow + c8 * 8) = o0;
            *(float4*)(orow + c8 * 8 + 4) = o1;
            *(uint4*)(srow + c8 * 8) = pb.v;
        }
    }
}

// ---------------- K4: MFMA att_feat = Mbf(bf16) @ AF (dbuf + swizzled LDS)
__global__ __launch_bounds__(256) void k_attgemm(const unsigned short* __restrict__ Mbf,
                                                 const unsigned short* __restrict__ AFT,
                                                 unsigned short* __restrict__ ATF) {
    __shared__ __bf16 As[2][128 * 32];
    __shared__ __bf16 Bs[2][128 * 32];
    const int t = threadIdx.x;
    const int jt = blockIdx.x, it = blockIdx.y, bl = blockIdx.z;
    const int i0 = it * 128, j0 = jt * 128;
    const int lane = t & 63, wv = t >> 6;
    const int wr = wv >> 1, wc = wv & 1;
    const int l15 = lane & 15;
    const int hix = (((lane >> 4) ^ ((l15 >> 1) & 3)) * 8);

    f32x4 zero = {0.f, 0.f, 0.f, 0.f};
    f32x4 acc[4][4];
#pragma unroll
    for (int m = 0; m < 4; ++m)
#pragma unroll
        for (int n = 0; n < 4; ++n) acc[m][n] = zero;

    const int s0 = t, s1 = t + 256;
    int ir0 = i0 + (s0 >> 2); if (ir0 > N_ - 1) ir0 = N_ - 1;
    int ir1 = i0 + (s1 >> 2); if (ir1 > N_ - 1) ir1 = N_ - 1;
    int jr0 = j0 + (s0 >> 2); if (jr0 > D_ - 1) jr0 = D_ - 1;
    int jr1 = j0 + (s1 >> 2); if (jr1 > D_ - 1) jr1 = D_ - 1;
    const int ac0 = (((s0 & 3) ^ ((s0 >> 3) & 3)) * 8);
    const int ac1 = (((s1 & 3) ^ ((s1 >> 3) & 3)) * 8);
    const unsigned short* a0 = Mbf + ((size_t)bl * N_ + ir0) * N_ + ac0;
    const unsigned short* a1 = Mbf + ((size_t)bl * N_ + ir1) * N_ + ac1;
    const unsigned short* b0 = AFT + (size_t)(bl * D_ + jr0) * N_ + ac0;
    const unsigned short* b1 = AFT + (size_t)(bl * D_ + jr1) * N_ + ac1;

    const int NT = N_ / 32;   // 87
    GLD16(a0 + 0, As[0] + s0 * 8);
    GLD16(a1 + 0, As[0] + s1 * 8);
    GLD16(b0 + 0, Bs[0] + s0 * 8);
    GLD16(b1 + 0, Bs[0] + s1 * 8);

    for (int kt = 0; kt < NT; ++kt) {
        const int cur = kt & 1;
        if (kt + 1 < NT) {
            const int nk = (kt + 1) * 32;
            GLD16(a0 + nk, As[cur ^ 1] + s0 * 8);
            GLD16(a1 + nk, As[cur ^ 1] + s1 * 8);
            GLD16(b0 + nk, Bs[cur ^ 1] + s0 * 8);
            GLD16(b1 + nk, Bs[cur ^ 1] + s1 * 8);
            asm volatile("s_waitcnt vmcnt(4)" ::: "memory");
        } else {
            asm volatile("s_waitcnt vmcnt(0)" ::: "memory");
        }
        __builtin_amdgcn_sched_barrier(0);
        __builtin_amdgcn_s_barrier();
        bf16x8 a[4], bb[4];
#pragma unroll
        for (int m = 0; m < 4; ++m)
            a[m] = *(const bf16x8*)(As[cur] + (wr * 64 + m * 16 + l15) * 32 + hix);
#pragma unroll
        for (int n = 0; n < 4; ++n)
            bb[n] = *(const bf16x8*)(Bs[cur] + (wc * 64 + n * 16 + l15) * 32 + hix);
#pragma unroll
        for (int m = 0; m < 4; ++m)
#pragma unroll
            for (int n = 0; n < 4; ++n)
                acc[m][n] = __builtin_amdgcn_mfma_f32_16x16x32_bf16(a[m], bb[n], acc[m][n], 0, 0, 0);
        __builtin_amdgcn_s_barrier();
        __builtin_amdgcn_sched_barrier(0);
    }

#pragma unroll
    for (int m = 0; m < 4; ++m) {
        int rb = i0 + wr * 64 + m * 16 + (lane >> 4) * 4;
#pragma unroll
        for (int n = 0; n < 4; ++n) {
            int d = j0 + wc * 64 + n * 16 + l15;
            if (d < D_) {
#pragma unroll
                for (int q = 0; q < 4; ++q) {
                    int rr = rb + q;
                    if (rr < N_)
                        ATF[((size_t)(bl * N_ + rr)) * D_ + d] = f2bf(acc[m][n][q]);
                }
            }
        }
    }
}

// ---------------- K5: MFMA heads + fused props epilogue (f32 out)
__global__ __launch_bounds__(256) void k_head(const unsigned short* __restrict__ ATF,
                                              const unsigned short* __restrict__ AF,
                                              const unsigned short* __restrict__ clsw,
                                              const unsigned short* __restrict__ clsb,
                                              const unsigned short* __restrict__ regw,
                                              const unsigned short* __restrict__ regb,
                                              const unsigned short* __restrict__ anch,
                                              float* __restrict__ props,
                                              int row_base, int nloc) {
    __shared__ __bf16 As[128 * 32];
    __shared__ __bf16 Ws[80 * 32];
    const int t = threadIdx.x;
    const int i0 = blockIdx.x * 128;
    const int lane = t & 63, wv = t >> 6;
    const int l15 = lane & 15, hi8 = (lane >> 4) * 8;

    f32x4 zero = {0.f, 0.f, 0.f, 0.f};
    f32x4 acc[2][5];
#pragma unroll
    for (int m = 0; m < 2; ++m)
#pragma unroll
        for (int n = 0; n < 5; ++n) acc[m][n] = zero;

    const int s0 = t, s1 = t + 256;
    const int ar0 = s0 >> 2, ac0 = (s0 & 3) * 8;
    const int ar1 = s1 >> 2, ac1 = (s1 & 3) * 8;
    int ir0 = i0 + ar0; if (ir0 > nloc - 1) ir0 = nloc - 1;
    int ir1 = i0 + ar1; if (ir1 > nloc - 1) ir1 = nloc - 1;
    const unsigned short* w0base = (ar0 < 2) ? (clsw + (size_t)ar0 * D2_)
                                             : (regw + (size_t)(ar0 - 2) * D2_);
    int r1 = 64 + (t >> 2);
    int rc = r1 < 75 ? r1 : 74;
    const unsigned short* w1base = regw + (size_t)(rc - 2) * D2_;
    const int w1c = (t & 3) * 8;

    for (int p = 0; p < 2; ++p) {
        const unsigned short* Asrc = (p == 0) ? ATF : AF;
        const int wcol = p * D_;
        for (int k0 = 0; k0 < D_; k0 += 32) {
            GLD16(Asrc + (size_t)ir0 * D_ + ac0 + k0, As + s0 * 8);
            GLD16(Asrc + (size_t)ir1 * D_ + ac1 + k0, As + s1 * 8);
            GLD16(w0base + wcol + k0 + ac0, Ws + s0 * 8);
            if (t < 64) GLD16(w1base + wcol + k0 + w1c, Ws + (size_t)(256 + t) * 8);
            __syncthreads();
            bf16x8 a[2], bb[5];
#pragma unroll
            for (int m = 0; m < 2; ++m)
                a[m] = *(const bf16x8*)(As + (wv * 32 + m * 16 + l15) * 32 + hi8);
#pragma unroll
            for (int n = 0; n < 5; ++n)
                bb[n] = *(const bf16x8*)(Ws + (n * 16 + l15) * 32 + hi8);
#pragma unroll
            for (int m = 0; m < 2; ++m)
#pragma unroll
                for (int n = 0; n < 5; ++n)
                    acc[m][n] = __builtin_amdgcn_mfma_f32_16x16x32_bf16(a[m], bb[n], acc[m][n], 0, 0, 0);
            __syncthreads();
        }
    }

#pragma unroll
    for (int m = 0; m < 2; ++m) {
        int ib = i0 + wv * 32 + m * 16 + (lane >> 4) * 4;
#pragma unroll
        for (int n = 0; n < 5; ++n) {
            int j = n * 16 + l15;
            if (j < 75) {
#pragma unroll
                for (int q = 0; q < 4; ++q) {
                    int i = ib + q;
                    if (i < nloc) {
                        size_t g = (size_t)(row_base + i);
                        int nn = i % N_;
                        float v = acc[m][n][q];
                        if (j < 2) {
                            props[g * PW_ + j] = v + bf2f(clsb[j]);
                            props[g * PW_ + 2 + j] = bf2f(anch[(size_t)nn * PW_ + 2 + j]);
                        } else {
                            int tt = j - 2;
                            props[g * PW_ + 4 + tt] = v + bf2f(regb[tt]) + bf2f(anch[(size_t)nn * PW_ + 4 + tt]);
                        }
                    }
                }
            }
        }
    }
}

extern "C" void kernel_launch(void* const* d_in, const int* in_sizes, int n_in,
                              void* d_out, int out_size, void* d_ws, size_t ws_size,
                              hipStream_t stream) {
    (void)in_sizes; (void)n_in; (void)out_size;

    float* props = (float*)d_out;
    float* Mbuf  = props + (size_t)ROWS_ * PW_;

    char* ws = (char*)d_ws;
    int* flags = (int*)(ws + OFF_FLAGS);
    float* feat = (float*)(ws + OFF_FEAT);
    char* canon = ws + OFF_CANON;
    unsigned short* cx    = (unsigned short*)(canon + C_X);
    unsigned short* cattw = (unsigned short*)(canon + C_ATTW);
    unsigned short* ccw   = (unsigned short*)(canon + C_CW);
    unsigned short* canch = (unsigned short*)(canon + C_ANCH);
    unsigned short* cclsw = (unsigned short*)(canon + C_CLSW);
    unsigned short* cregw = (unsigned short*)(canon + C_REGW);
    unsigned short* ccb   = (unsigned short*)(canon + C_CB);
    unsigned short* cattb = (unsigned short*)(canon + C_ATTB);
    unsigned short* cclsb = (unsigned short*)(canon + C_CLSB);
    unsigned short* cregb = (unsigned short*)(canon + C_REGB);
    int* ccut = (int*)(canon + C_CUT);
    int* cmsk = (int*)(canon + C_MASK);

    // per-batch ws need: AF/AFT/ATF (3 * N*D*2) + Mbf (N*N*2)
    const size_t base = (size_t)(12u << 20);
    const size_t sAF  = (size_t)N_ * D_ * 2;           // 3,919,872
    const size_t sMB  = (size_t)N_ * N_ * 2;           // 15,501,312
    const size_t per  = 3 * sAF + sMB;                 // ~27.3 MB
    int CN = 1;
    for (int c = 16; c >= 1; c >>= 1)
        if (ws_size >= base + (size_t)c * per) { CN = c; break; }
    unsigned short* AF  = (unsigned short*)(ws + base);
    unsigned short* AFT = AF  + (size_t)CN * N_ * D_;
    unsigned short* ATF = AFT + (size_t)CN * N_ * D_;
    unsigned short* Mbf = ATF + (size_t)CN * N_ * D_;

    k_detect<<<dim3(1), dim3(256), 0, stream>>>((const unsigned int*)d_in[3],
                                                (const unsigned int*)d_in[10],
                                                (const unsigned int*)d_in[11], flags);
    k_canon_f<<<dim3(1024), dim3(256), 0, stream>>>(d_in[0], d_in[1], d_in[2], d_in[3], d_in[4],
                                                    d_in[5], d_in[6], d_in[7], d_in[8], d_in[9],
                                                    canon, flags);
    k_canon_i<<<dim3(120), dim3(256), 0, stream>>>(d_in[10], d_in[11], canon, flags);
    k_conv<<<dim3(880), dim3(256), 0, stream>>>(cx, ccw, ccb, feat);

    const int nchunk = 16 / CN;
    for (int c = 0; c < nchunk; ++c) {
        const int bb = c * CN;
        const int rb = bb * N_;
        const int nl = CN * N_;
        const int it128 = (nl + 127) / 128;
        k_gather_af<<<dim3(N_, CN), dim3(256), 0, stream>>>(feat, ccut, cmsk, AF, bb);
        k_gather_aft<<<dim3(D_, CN), dim3(256), 0, stream>>>(feat, ccut, cmsk, AFT, bb);
        k_scores<<<dim3(22, it128), dim3(256), 0, stream>>>(AF, cattw, cattb, Mbf, nl);
        k_softmax<<<dim3(nl), dim3(256), 0, stream>>>(Mbf, Mbuf, rb);
        k_attgemm<<<dim3(6, 22, CN), dim3(256), 0, stream>>>(Mbf, AFT, ATF);
        k_head<<<dim3(it128), dim3(256), 0, stream>>>(ATF, AF, cclsw, cclsb, cregw, cregb,
                                                      canch, props, rb, nl);
    }
}

// Round 9
// 1023.771 us; speedup vs baseline: 21.6420x; 1.0551x over previous
//
#include <hip/hip_runtime.h>

#define B_    16
#define CIN_  512
#define CF_   64
#define FH_   11
#define FW_   20
#define N_    2784
#define NM1_  2783
#define D_    704
#define D2_   1408
#define ROWS_ 44544
#define PW_   77

// ---- input element counts
#define NX_     1802240
#define NCW_    32768
#define NCB_    64
#define NATTW_  1959232
#define NATTB_  2783
#define NCLSW_  2816
#define NCLSB_  2
#define NREGW_  102784
#define NREGB_  73
#define NANCH_  214368
#define NCUT_   30624

// ---- canonical ws layout (byte offsets)
#define OFF_FLAGS   0u
#define OFF_FEAT    256u
#define OFF_CANON   (1u<<20)
#define C_X      0u
#define C_ATTW   3604480u
#define C_CW     7522944u
#define C_ANCH   7588480u
#define C_CLSW   8017216u
#define C_REGW   8022848u
#define C_CB     8228416u
#define C_ATTB   8228544u
#define C_CLSB   8234112u
#define C_REGB   8234128u
#define C_CUT    8234288u
#define C_MASK   8356784u

typedef __bf16 bf16x8 __attribute__((ext_vector_type(8)));
typedef float  f32x4  __attribute__((ext_vector_type(4)));

typedef __attribute__((address_space(1))) void g_void;
typedef __attribute__((address_space(3))) void l_void;
#define GLD16(gp, lp) __builtin_amdgcn_global_load_lds((g_void*)(gp), (l_void*)(lp), 16, 0, 0)

__device__ __forceinline__ float bf2f(unsigned short u) {
    union { unsigned int u; float f; } v; v.u = ((unsigned int)u) << 16; return v.f;
}
__device__ __forceinline__ unsigned short f2bf(float f) {
    union { float f; unsigned int u; } v; v.f = f;
    unsigned int x = v.u;
    return (unsigned short)((x + 0x7FFFu + ((x >> 16) & 1u)) >> 16);
}

// m204 bijective XCD swizzle: same-XCD blocks get contiguous work ids
__device__ __forceinline__ int swz8(int olid, int nwg) {
    int xcd = olid & 7, pos = olid >> 3;
    int q = nwg >> 3, r = nwg & 7;
    int off = (xcd < r) ? xcd * (q + 1) : r * (q + 1) + (xcd - r) * q;
    return off + pos;
}

// ---------------- K0: dtype detection (deterministic, input-only)
__global__ __launch_bounds__(256) void k_detect(const unsigned int* __restrict__ attw,
                                                const unsigned int* __restrict__ cut,
                                                const unsigned int* __restrict__ msk,
                                                int* __restrict__ flags) {
    __shared__ int cnt[3];
    int t = threadIdx.x;
    if (t < 3) cnt[t] = 0;
    __syncthreads();
    int c0 = 0, c1 = 0, c2 = 0;
    for (int i = t; i < 2048; i += 256) {
        unsigned int e = (attw[i] >> 7) & 0xFFu;
        if (e >= 127u) c0++;
    }
    for (int i = t; i < 4096; i += 256) if (cut[i] >= 32u) c1++;
    for (int i = t; i < 4096; i += 256) if (msk[i] >= 2u)  c2++;
    atomicAdd(&cnt[0], c0); atomicAdd(&cnt[1], c1); atomicAdd(&cnt[2], c2);
    __syncthreads();
    if (t == 0) {
        flags[0] = cnt[0] > 64;
        flags[1] = cnt[1] > 64;
        flags[2] = cnt[2] > 64;
        flags[3] = 0;
    }
}

// ---------------- K0b: canonicalize all float inputs to bf16
__device__ __forceinline__ void cvt_arr(const void* s, unsigned short* d, int n, int isf32,
                                        int tid, int stride) {
    if (isf32) {
        const float* p = (const float*)s;
        for (int i = tid; i < n; i += stride) d[i] = f2bf(p[i]);
    } else {
        const unsigned short* p = (const unsigned short*)s;
        for (int i = tid; i < n; i += stride) d[i] = p[i];
    }
}

__global__ __launch_bounds__(256) void k_canon_f(const void* sx, const void* scw, const void* scb,
                                                 const void* sattw, const void* sattb,
                                                 const void* sclsw, const void* sclsb,
                                                 const void* sregw, const void* sregb,
                                                 const void* sanch, char* canon,
                                                 const int* __restrict__ flags) {
    const int isf32 = flags[0];
    const int tid = blockIdx.x * 256 + threadIdx.x;
    const int stride = gridDim.x * 256;
    cvt_arr(sx,    (unsigned short*)(canon + C_X),    NX_,    isf32, tid, stride);
    cvt_arr(sattw, (unsigned short*)(canon + C_ATTW), NATTW_, isf32, tid, stride);
    cvt_arr(scw,   (unsigned short*)(canon + C_CW),   NCW_,   isf32, tid, stride);
    cvt_arr(sanch, (unsigned short*)(canon + C_ANCH), NANCH_, isf32, tid, stride);
    cvt_arr(sclsw, (unsigned short*)(canon + C_CLSW), NCLSW_, isf32, tid, stride);
    cvt_arr(sregw, (unsigned short*)(canon + C_REGW), NREGW_, isf32, tid, stride);
    cvt_arr(scb,   (unsigned short*)(canon + C_CB),   NCB_,   isf32, tid, stride);
    cvt_arr(sattb, (unsigned short*)(canon + C_ATTB), NATTB_, isf32, tid, stride);
    cvt_arr(sclsb, (unsigned short*)(canon + C_CLSB), NCLSB_, isf32, tid, stride);
    cvt_arr(sregb, (unsigned short*)(canon + C_REGB), NREGB_, isf32, tid, stride);
}

// ---------------- K0c: canonicalize int inputs to int32
__global__ __launch_bounds__(256) void k_canon_i(const void* scut, const void* smsk,
                                                 char* canon, const int* __restrict__ flags) {
    const int cutb = flags[1], mskb = flags[2];
    int* ccut = (int*)(canon + C_CUT);
    int* cmsk = (int*)(canon + C_MASK);
    const int tid = blockIdx.x * 256 + threadIdx.x;
    const int stride = gridDim.x * 256;
    for (int i = tid; i < NCUT_; i += stride) {
        ccut[i] = cutb ? (int)((const unsigned char*)scut)[i] : ((const int*)scut)[i];
        int m = mskb ? (int)((const unsigned char*)smsk)[i] : ((const int*)smsk)[i];
        cmsk[i] = (m != 0);
    }
}

// ---------------- K1: 1x1 conv
__global__ __launch_bounds__(256) void k_conv(const unsigned short* __restrict__ x,
                                              const unsigned short* __restrict__ cw,
                                              const unsigned short* __restrict__ cb,
                                              float* __restrict__ feat) {
    int idx = blockIdx.x * 256 + threadIdx.x;           // 880*256 = 225280 exact
    int w = idx % FW_;
    int h = (idx / FW_) % FH_;
    int o = (idx / (FW_ * FH_)) % CF_;
    int b = idx / (FW_ * FH_ * CF_);
    const unsigned short* xp = x + ((size_t)(b * CIN_) * FH_ + h) * FW_ + w;
    const unsigned short* wp = cw + (size_t)o * CIN_;
    float acc = bf2f(cb[o]);
#pragma unroll 8
    for (int c = 0; c < CIN_; ++c)
        acc += bf2f(xp[(size_t)c * (FH_ * FW_)]) * bf2f(wp[c]);
    feat[idx] = acc;
}

// ---------------- K2a: AF chunk
__global__ __launch_bounds__(256) void k_gather_af(const float* __restrict__ feat,
                                                   const int* __restrict__ cut,
                                                   const int* __restrict__ inv,
                                                   unsigned short* __restrict__ AF,
                                                   int batch_base) {
    int n = blockIdx.x, bl = blockIdx.y;
    int b = batch_base + bl;
    __shared__ int cu[FH_];
    __shared__ int iv[FH_];
    int t = threadIdx.x;
    if (t < FH_) { cu[t] = cut[n * FH_ + t]; iv[t] = inv[n * FH_ + t]; }
    __syncthreads();
    unsigned short* out = AF + ((size_t)(bl * N_ + n)) * D_;
    for (int d = t; d < D_; d += 256) {
        int c = d / FH_, h = d - c * FH_;
        float v = iv[h] ? 0.f : feat[((b * CF_ + c) * FH_ + h) * FW_ + cu[h]];
        out[d] = f2bf(v);
    }
}

// ---------------- K2b: AFT chunk
__global__ __launch_bounds__(256) void k_gather_aft(const float* __restrict__ feat,
                                                    const int* __restrict__ cut,
                                                    const int* __restrict__ inv,
                                                    unsigned short* __restrict__ AFT,
                                                    int batch_base) {
    int d = blockIdx.x, bl = blockIdx.y;
    int b = batch_base + bl;
    int c = d / FH_, h = d - c * FH_;
    const float* fp = feat + ((b * CF_ + c) * FH_ + h) * FW_;
    unsigned short* out = AFT + ((size_t)(bl * D_ + d)) * N_;
    for (int n = threadIdx.x; n < N_; n += 256) {
        int w = cut[n * FH_ + h];
        float v = inv[n * FH_ + h] ? 0.f : fp[w];
        out[n] = f2bf(v);
    }
}

// ---------------- K3a: MFMA scores GEMM (dbuf + swizzled LDS + XCD swizzle), bf16 scores -> Mbf
__global__ __launch_bounds__(256) void k_scores(const unsigned short* __restrict__ AF,
                                                const unsigned short* __restrict__ attw,
                                                const unsigned short* __restrict__ attb,
                                                unsigned short* __restrict__ Mbf,
                                                int nloc) {
    __shared__ __bf16 As[2][128 * 32];
    __shared__ __bf16 Bs[2][128 * 32];
    const int t = threadIdx.x;
    const int nwg = gridDim.x * gridDim.y;
    const int olid = blockIdx.x + gridDim.x * blockIdx.y;
    const int nid = swz8(olid, nwg);
    const int jt = nid % 22, it = nid / 22;
    const int i0 = it * 128, j0 = jt * 128;
    const int lane = t & 63, wv = t >> 6;
    const int wr = wv >> 1, wc = wv & 1;
    const int l15 = lane & 15;
    const int hix = (((lane >> 4) ^ ((l15 >> 1) & 3)) * 8);

    f32x4 zero = {0.f, 0.f, 0.f, 0.f};
    f32x4 acc[4][4];
#pragma unroll
    for (int m = 0; m < 4; ++m)
#pragma unroll
        for (int n = 0; n < 4; ++n) acc[m][n] = zero;

    const int s0 = t, s1 = t + 256;
    const int ar0 = s0 >> 2, ar1 = s1 >> 2;
    const int ac0 = (((s0 & 3) ^ ((s0 >> 3) & 3)) * 8);
    const int ac1 = (((s1 & 3) ^ ((s1 >> 3) & 3)) * 8);
    int ir0 = i0 + ar0; if (ir0 > nloc - 1) ir0 = nloc - 1;
    int ir1 = i0 + ar1; if (ir1 > nloc - 1) ir1 = nloc - 1;
    int jr0 = j0 + ar0; if (jr0 > NM1_ - 1) jr0 = NM1_ - 1;
    int jr1 = j0 + ar1; if (jr1 > NM1_ - 1) jr1 = NM1_ - 1;
    const unsigned short* a0 = AF + (size_t)ir0 * D_ + ac0;
    const unsigned short* a1 = AF + (size_t)ir1 * D_ + ac1;
    const unsigned short* b0 = attw + (size_t)jr0 * D_ + ac0;
    const unsigned short* b1 = attw + (size_t)jr1 * D_ + ac1;

    const int NT = D_ / 32;   // 22
    GLD16(a0 + 0, As[0] + s0 * 8);
    GLD16(a1 + 0, As[0] + s1 * 8);
    GLD16(b0 + 0, Bs[0] + s0 * 8);
    GLD16(b1 + 0, Bs[0] + s1 * 8);

    for (int kt = 0; kt < NT; ++kt) {
        const int cur = kt & 1;
        if (kt + 1 < NT) {
            const int nk = (kt + 1) * 32;
            GLD16(a0 + nk, As[cur ^ 1] + s0 * 8);
            GLD16(a1 + nk, As[cur ^ 1] + s1 * 8);
            GLD16(b0 + nk, Bs[cur ^ 1] + s0 * 8);
            GLD16(b1 + nk, Bs[cur ^ 1] + s1 * 8);
            asm volatile("s_waitcnt vmcnt(4)" ::: "memory");
        } else {
            asm volatile("s_waitcnt vmcnt(0)" ::: "memory");
        }
        __builtin_amdgcn_sched_barrier(0);
        __builtin_amdgcn_s_barrier();
        bf16x8 a[4], bb[4];
#pragma unroll
        for (int m = 0; m < 4; ++m)
            a[m] = *(const bf16x8*)(As[cur] + (wr * 64 + m * 16 + l15) * 32 + hix);
#pragma unroll
        for (int n = 0; n < 4; ++n)
            bb[n] = *(const bf16x8*)(Bs[cur] + (wc * 64 + n * 16 + l15) * 32 + hix);
#pragma unroll
        for (int m = 0; m < 4; ++m)
#pragma unroll
            for (int n = 0; n < 4; ++n)
                acc[m][n] = __builtin_amdgcn_mfma_f32_16x16x32_bf16(a[m], bb[n], acc[m][n], 0, 0, 0);
        __builtin_amdgcn_s_barrier();
        __builtin_amdgcn_sched_barrier(0);
    }

#pragma unroll
    for (int m = 0; m < 4; ++m) {
        int ib = i0 + wr * 64 + m * 16 + (lane >> 4) * 4;
#pragma unroll
        for (int n = 0; n < 4; ++n) {
            int j = j0 + wc * 64 + n * 16 + l15;
            if (j < NM1_) {
                float bias = bf2f(attb[j]);
#pragma unroll
                for (int q = 0; q < 4; ++q) {
                    int ii = ib + q;
                    if (ii < nloc) {
                        int r = ii % N_;
                        int c = j + (j >= r);
                        Mbf[(size_t)ii * N_ + c] = f2bf(acc[m][n][q] + bias);
                    }
                }
            }
        }
    }
}

// ---------------- K3b: bf16 row softmax IN PLACE + f32 M write to d_out (diag -> exact 0)
__global__ __launch_bounds__(256) void k_softmax(unsigned short* __restrict__ Mbf,
                                                 float* __restrict__ Mout,
                                                 int row_base) {
    const int il = blockIdx.x;
    const int r = il % N_;
    unsigned short* srow = Mbf + (size_t)il * N_;
    float* orow = Mout + (size_t)(row_base + il) * N_;
    const int t = threadIdx.x;
    float f[16];
#pragma unroll
    for (int q = 0; q < 2; ++q) {
        int c8 = t + 256 * q;
        if (c8 < N_ / 8) {
            uint4 u = *(const uint4*)(srow + c8 * 8);
            const unsigned short* pu = (const unsigned short*)&u;
#pragma unroll
            for (int e = 0; e < 8; ++e) {
                int c = c8 * 8 + e;
                float v = bf2f(pu[e]);
                f[q * 8 + e] = (c == r) ? -1e30f : v;
            }
        } else {
#pragma unroll
            for (int e = 0; e < 8; ++e) f[q * 8 + e] = -1e30f;
        }
    }
    float m = -1e30f;
#pragma unroll
    for (int q = 0; q < 16; ++q) m = fmaxf(m, f[q]);
#pragma unroll
    for (int off = 32; off >= 1; off >>= 1) m = fmaxf(m, __shfl_xor(m, off, 64));
    __shared__ float red[4];
    if ((t & 63) == 0) red[t >> 6] = m;
    __syncthreads();
    m = fmaxf(fmaxf(red[0], red[1]), fmaxf(red[2], red[3]));

    float s = 0.f;
#pragma unroll
    for (int q = 0; q < 16; ++q) { float e = __expf(f[q] - m); f[q] = e; s += e; }
#pragma unroll
    for (int off = 32; off >= 1; off >>= 1) s += __shfl_xor(s, off, 64);
    __shared__ float red2[4];
    if ((t & 63) == 0) red2[t >> 6] = s;
    __syncthreads();
    s = red2[0] + red2[1] + red2[2] + red2[3];
    float inv = 1.0f / s;
#pragma unroll
    for (int q = 0; q < 2; ++q) {
        int c8 = t + 256 * q;
        if (c8 < N_ / 8) {
            float o[8];
            union { unsigned short u[8]; uint4 v; } pb;
#pragma unroll
            for (int e = 0; e < 8; ++e) {
                o[e] = f[q * 8 + e] * inv;     // diag: exp(-1e30-m)=0 -> exact 0
                pb.u[e] = f2bf(o[e]);
            }
            float4 o0 = {o[0], o[1], o[2], o[3]};
            float4 o1 = {o[4], o[5], o[6], o[7]};
            *(float4*)(orow + c8 * 8) = o0;
            *(float4*)(orow + c8 * 8 + 4) = o1;
            *(uint4*)(srow + c8 * 8) = pb.v;
        }
    }
}

// ---------------- K4: MFMA att_feat = Mbf(bf16) @ AF (dbuf + swizzled LDS + XCD swizzle)
__global__ __launch_bounds__(256) void k_attgemm(const unsigned short* __restrict__ Mbf,
                                                 const unsigned short* __restrict__ AFT,
                                                 unsigned short* __restrict__ ATF) {
    __shared__ __bf16 As[2][128 * 32];
    __shared__ __bf16 Bs[2][128 * 32];
    const int t = threadIdx.x;
    const int nwg = gridDim.x * gridDim.y * gridDim.z;
    const int olid = blockIdx.x + gridDim.x * (blockIdx.y + gridDim.y * blockIdx.z);
    const int nid = swz8(olid, nwg);
    const int jt = nid % 6, it = (nid / 6) % 22, bl = nid / 132;
    const int i0 = it * 128, j0 = jt * 128;
    const int lane = t & 63, wv = t >> 6;
    const int wr = wv >> 1, wc = wv & 1;
    const int l15 = lane & 15;
    const int hix = (((lane >> 4) ^ ((l15 >> 1) & 3)) * 8);

    f32x4 zero = {0.f, 0.f, 0.f, 0.f};
    f32x4 acc[4][4];
#pragma unroll
    for (int m = 0; m < 4; ++m)
#pragma unroll
        for (int n = 0; n < 4; ++n) acc[m][n] = zero;

    const int s0 = t, s1 = t + 256;
    int ir0 = i0 + (s0 >> 2); if (ir0 > N_ - 1) ir0 = N_ - 1;
    int ir1 = i0 + (s1 >> 2); if (ir1 > N_ - 1) ir1 = N_ - 1;
    int jr0 = j0 + (s0 >> 2); if (jr0 > D_ - 1) jr0 = D_ - 1;
    int jr1 = j0 + (s1 >> 2); if (jr1 > D_ - 1) jr1 = D_ - 1;
    const int ac0 = (((s0 & 3) ^ ((s0 >> 3) & 3)) * 8);
    const int ac1 = (((s1 & 3) ^ ((s1 >> 3) & 3)) * 8);
    const unsigned short* a0 = Mbf + ((size_t)bl * N_ + ir0) * N_ + ac0;
    const unsigned short* a1 = Mbf + ((size_t)bl * N_ + ir1) * N_ + ac1;
    const unsigned short* b0 = AFT + (size_t)(bl * D_ + jr0) * N_ + ac0;
    const unsigned short* b1 = AFT + (size_t)(bl * D_ + jr1) * N_ + ac1;

    const int NT = N_ / 32;   // 87
    GLD16(a0 + 0, As[0] + s0 * 8);
    GLD16(a1 + 0, As[0] + s1 * 8);
    GLD16(b0 + 0, Bs[0] + s0 * 8);
    GLD16(b1 + 0, Bs[0] + s1 * 8);

    for (int kt = 0; kt < NT; ++kt) {
        const int cur = kt & 1;
        if (kt + 1 < NT) {
            const int nk = (kt + 1) * 32;
            GLD16(a0 + nk, As[cur ^ 1] + s0 * 8);
            GLD16(a1 + nk, As[cur ^ 1] + s1 * 8);
            GLD16(b0 + nk, Bs[cur ^ 1] + s0 * 8);
            GLD16(b1 + nk, Bs[cur ^ 1] + s1 * 8);
            asm volatile("s_waitcnt vmcnt(4)" ::: "memory");
        } else {
            asm volatile("s_waitcnt vmcnt(0)" ::: "memory");
        }
        __builtin_amdgcn_sched_barrier(0);
        __builtin_amdgcn_s_barrier();
        bf16x8 a[4], bb[4];
#pragma unroll
        for (int m = 0; m < 4; ++m)
            a[m] = *(const bf16x8*)(As[cur] + (wr * 64 + m * 16 + l15) * 32 + hix);
#pragma unroll
        for (int n = 0; n < 4; ++n)
            bb[n] = *(const bf16x8*)(Bs[cur] + (wc * 64 + n * 16 + l15) * 32 + hix);
#pragma unroll
        for (int m = 0; m < 4; ++m)
#pragma unroll
            for (int n = 0; n < 4; ++n)
                acc[m][n] = __builtin_amdgcn_mfma_f32_16x16x32_bf16(a[m], bb[n], acc[m][n], 0, 0, 0);
        __builtin_amdgcn_s_barrier();
        __builtin_amdgcn_sched_barrier(0);
    }

#pragma unroll
    for (int m = 0; m < 4; ++m) {
        int rb = i0 + wr * 64 + m * 16 + (lane >> 4) * 4;
#pragma unroll
        for (int n = 0; n < 4; ++n) {
            int d = j0 + wc * 64 + n * 16 + l15;
            if (d < D_) {
#pragma unroll
                for (int q = 0; q < 4; ++q) {
                    int rr = rb + q;
                    if (rr < N_)
                        ATF[((size_t)(bl * N_ + rr)) * D_ + d] = f2bf(acc[m][n][q]);
                }
            }
        }
    }
}

// ---------------- K5: MFMA heads + fused props epilogue (f32 out)
__global__ __launch_bounds__(256) void k_head(const unsigned short* __restrict__ ATF,
                                              const unsigned short* __restrict__ AF,
                                              const unsigned short* __restrict__ clsw,
                                              const unsigned short* __restrict__ clsb,
                                              const unsigned short* __restrict__ regw,
                                              const unsigned short* __restrict__ regb,
                                              const unsigned short* __restrict__ anch,
                                              float* __restrict__ props,
                                              int row_base, int nloc) {
    __shared__ __bf16 As[128 * 32];
    __shared__ __bf16 Ws[80 * 32];
    const int t = threadIdx.x;
    const int i0 = blockIdx.x * 128;
    const int lane = t & 63, wv = t >> 6;
    const int l15 = lane & 15, hi8 = (lane >> 4) * 8;

    f32x4 zero = {0.f, 0.f, 0.f, 0.f};
    f32x4 acc[2][5];
#pragma unroll
    for (int m = 0; m < 2; ++m)
#pragma unroll
        for (int n = 0; n < 5; ++n) acc[m][n] = zero;

    const int s0 = t, s1 = t + 256;
    const int ar0 = s0 >> 2, ac0 = (s0 & 3) * 8;
    const int ar1 = s1 >> 2, ac1 = (s1 & 3) * 8;
    int ir0 = i0 + ar0; if (ir0 > nloc - 1) ir0 = nloc - 1;
    int ir1 = i0 + ar1; if (ir1 > nloc - 1) ir1 = nloc - 1;
    const unsigned short* w0base = (ar0 < 2) ? (clsw + (size_t)ar0 * D2_)
                                             : (regw + (size_t)(ar0 - 2) * D2_);
    int r1 = 64 + (t >> 2);
    int rc = r1 < 75 ? r1 : 74;
    const unsigned short* w1base = regw + (size_t)(rc - 2) * D2_;
    const int w1c = (t & 3) * 8;

    for (int p = 0; p < 2; ++p) {
        const unsigned short* Asrc = (p == 0) ? ATF : AF;
        const int wcol = p * D_;
        for (int k0 = 0; k0 < D_; k0 += 32) {
            GLD16(Asrc + (size_t)ir0 * D_ + ac0 + k0, As + s0 * 8);
            GLD16(Asrc + (size_t)ir1 * D_ + ac1 + k0, As + s1 * 8);
            GLD16(w0base + wcol + k0 + ac0, Ws + s0 * 8);
            if (t < 64) GLD16(w1base + wcol + k0 + w1c, Ws + (size_t)(256 + t) * 8);
            __syncthreads();
            bf16x8 a[2], bb[5];
#pragma unroll
            for (int m = 0; m < 2; ++m)
                a[m] = *(const bf16x8*)(As + (wv * 32 + m * 16 + l15) * 32 + hi8);
#pragma unroll
            for (int n = 0; n < 5; ++n)
                bb[n] = *(const bf16x8*)(Ws + (n * 16 + l15) * 32 + hi8);
#pragma unroll
            for (int m = 0; m < 2; ++m)
#pragma unroll
                for (int n = 0; n < 5; ++n)
                    acc[m][n] = __builtin_amdgcn_mfma_f32_16x16x32_bf16(a[m], bb[n], acc[m][n], 0, 0, 0);
            __syncthreads();
        }
    }

#pragma unroll
    for (int m = 0; m < 2; ++m) {
        int ib = i0 + wv * 32 + m * 16 + (lane >> 4) * 4;
#pragma unroll
        for (int n = 0; n < 5; ++n) {
            int j = n * 16 + l15;
            if (j < 75) {
#pragma unroll
                for (int q = 0; q < 4; ++q) {
                    int i = ib + q;
                    if (i < nloc) {
                        size_t g = (size_t)(row_base + i);
                        int nn = i % N_;
                        float v = acc[m][n][q];
                        if (j < 2) {
                            props[g * PW_ + j] = v + bf2f(clsb[j]);
                            props[g * PW_ + 2 + j] = bf2f(anch[(size_t)nn * PW_ + 2 + j]);
                        } else {
                            int tt = j - 2;
                            props[g * PW_ + 4 + tt] = v + bf2f(regb[tt]) + bf2f(anch[(size_t)nn * PW_ + 4 + tt]);
                        }
                    }
                }
            }
        }
    }
}

extern "C" void kernel_launch(void* const* d_in, const int* in_sizes, int n_in,
                              void* d_out, int out_size, void* d_ws, size_t ws_size,
                              hipStream_t stream) {
    (void)in_sizes; (void)n_in; (void)out_size;

    float* props = (float*)d_out;
    float* Mbuf  = props + (size_t)ROWS_ * PW_;

    char* ws = (char*)d_ws;
    int* flags = (int*)(ws + OFF_FLAGS);
    float* feat = (float*)(ws + OFF_FEAT);
    char* canon = ws + OFF_CANON;
    unsigned short* cx    = (unsigned short*)(canon + C_X);
    unsigned short* cattw = (unsigned short*)(canon + C_ATTW);
    unsigned short* ccw   = (unsigned short*)(canon + C_CW);
    unsigned short* canch = (unsigned short*)(canon + C_ANCH);
    unsigned short* cclsw = (unsigned short*)(canon + C_CLSW);
    unsigned short* cregw = (unsigned short*)(canon + C_REGW);
    unsigned short* ccb   = (unsigned short*)(canon + C_CB);
    unsigned short* cattb = (unsigned short*)(canon + C_ATTB);
    unsigned short* cclsb = (unsigned short*)(canon + C_CLSB);
    unsigned short* cregb = (unsigned short*)(canon + C_REGB);
    int* ccut = (int*)(canon + C_CUT);
    int* cmsk = (int*)(canon + C_MASK);

    // per-batch ws need: AF/AFT/ATF (3 * N*D*2) + Mbf (N*N*2)
    const size_t base = (size_t)(12u << 20);
    const size_t sAF  = (size_t)N_ * D_ * 2;           // 3,919,872
    const size_t sMB  = (size_t)N_ * N_ * 2;           // 15,501,312
    const size_t per  = 3 * sAF + sMB;                 // ~27.3 MB
    int CN = 1;
    for (int c = 16; c >= 1; c >>= 1)
        if (ws_size >= base + (size_t)c * per) { CN = c; break; }
    unsigned short* AF  = (unsigned short*)(ws + base);
    unsigned short* AFT = AF  + (size_t)CN * N_ * D_;
    unsigned short* ATF = AFT + (size_t)CN * N_ * D_;
    unsigned short* Mbf = ATF + (size_t)CN * N_ * D_;

    k_detect<<<dim3(1), dim3(256), 0, stream>>>((const unsigned int*)d_in[3],
                                                (const unsigned int*)d_in[10],
                                                (const unsigned int*)d_in[11], flags);
    k_canon_f<<<dim3(1024), dim3(256), 0, stream>>>(d_in[0], d_in[1], d_in[2], d_in[3], d_in[4],
                                                    d_in[5], d_in[6], d_in[7], d_in[8], d_in[9],
                                                    canon, flags);
    k_canon_i<<<dim3(120), dim3(256), 0, stream>>>(d_in[10], d_in[11], canon, flags);
    k_conv<<<dim3(880), dim3(256), 0, stream>>>(cx, ccw, ccb, feat);

    const int nchunk = 16 / CN;
    for (int c = 0; c < nchunk; ++c) {
        const int bb = c * CN;
        const int rb = bb * N_;
        const int nl = CN * N_;
        const int it128 = (nl + 127) / 128;
        k_gather_af<<<dim3(N_, CN), dim3(256), 0, stream>>>(feat, ccut, cmsk, AF, bb);
        k_gather_aft<<<dim3(D_, CN), dim3(256), 0, stream>>>(feat, ccut, cmsk, AFT, bb);
        k_scores<<<dim3(22, it128), dim3(256), 0, stream>>>(AF, cattw, cattb, Mbf, nl);
        k_softmax<<<dim3(nl), dim3(256), 0, stream>>>(Mbf, Mbuf, rb);
        k_attgemm<<<dim3(6, 22, CN), dim3(256), 0, stream>>>(Mbf, AFT, ATF);
        k_head<<<dim3(it128), dim3(256), 0, stream>>>(ATF, AF, cclsw, cclsb, cregw, cregb,
                                                      canch, props, rb, nl);
    }
}